// Round 5
// baseline (1957.373 us; speedup 1.0000x reference)
//
#include <hip/hip_runtime.h>
#include <math.h>

// ============================================================================
// GeometricModule: KNN(20) -> PCA normal/curvature (LAPACK-replica eigh) ->
// local dist feats -> per-point MLP 9->64->128->256, out (B,256,N) f32.
//
// R5: LDS-staged scan. R4's scan serialized global loads (VGPR=36 register
//     minimization) -> latency-bound. Now candidates live in LDS planar
//     sx/sy/sz (48KB), scan reads = ds_read_b128 broadcast; 2 blocks/CU.
//     feat/mlp/prep identical to R4 (passed). Eig path byte-identical R1-R4.
// ============================================================================

#define LARTG_NEW 1
#define NPT 4096
#define KNN 20
#define CAPS 64   // pooled per-query collect capacity
#define QPB 32    // queries per scan block

// ---------------- LAPACK f32 helper replicas ----------------

__device__ __forceinline__ float slapy2f(float x, float y) {
#pragma clang fp contract(off)
  float xa = fabsf(x), ya = fabsf(y);
  float w = fmaxf(xa, ya);
  float z = fminf(xa, ya);
  if (z == 0.f) return w;
  float q = z / w;
  return w * sqrtf(1.f + q * q);
}

__device__ __forceinline__ void slartgf(float f, float g, float* cs, float* sn, float* rr) {
#pragma clang fp contract(off)
#if LARTG_NEW
  const float safmin = 1.17549435e-38f;
  const float safmax = 8.5070592e37f;
  const float rtmin  = 1.0842022e-19f;
  const float rtmax  = 6.5221643e18f;
  float f1 = fabsf(f), g1 = fabsf(g);
  if (g == 0.f) { *cs = 1.f; *sn = 0.f; *rr = f; }
  else if (f == 0.f) { *cs = 0.f; *sn = copysignf(1.f, g); *rr = g1; }
  else {
    if (f1 > rtmin && f1 < rtmax && g1 > rtmin && g1 < rtmax) {
      float dd = sqrtf(f * f + g * g);
      *cs = f1 / dd;
      float r = copysignf(dd, f);
      *sn = g / r;
      *rr = r;
    } else {
      float u = fminf(safmax, fmaxf(safmin, fmaxf(f1, g1)));
      float fs = f / u, gs = g / u;
      float dd = sqrtf(fs * fs + gs * gs);
      *cs = fabsf(fs) / dd;
      float r = copysignf(dd, f);
      *sn = gs / r;
      *rr = r * u;
    }
  }
#else
  if (g == 0.f) { *cs = 1.f; *sn = 0.f; *rr = f; }
  else if (f == 0.f) { *cs = 0.f; *sn = 1.f; *rr = g; }
  else {
    float r = sqrtf(f * f + g * g);
    float c = f / r, s = g / r;
    if (fabsf(f) > fabsf(g) && c < 0.f) { c = -c; s = -s; r = -r; }
    *cs = c; *sn = s; *rr = r;
  }
#endif
}

__device__ __forceinline__ void slaev2f(float a, float b, float c,
                                        float* rt1, float* rt2, float* cs1, float* sn1) {
#pragma clang fp contract(off)
  float sm = a + c, df = a - c, adf = fabsf(df);
  float tb = b + b, ab = fabsf(tb);
  float acmx, acmn;
  if (fabsf(a) > fabsf(c)) { acmx = a; acmn = c; } else { acmx = c; acmn = a; }
  float rt;
  if (adf > ab)      { float t = ab / adf; rt = adf * sqrtf(1.f + t * t); }
  else if (adf < ab) { float t = adf / ab; rt = ab * sqrtf(1.f + t * t); }
  else               { rt = ab * sqrtf(2.f); }
  int sgn1;
  if (sm < 0.f)      { *rt1 = 0.5f * (sm - rt); sgn1 = -1; *rt2 = (acmx / *rt1) * acmn - (b / *rt1) * b; }
  else if (sm > 0.f) { *rt1 = 0.5f * (sm + rt); sgn1 = 1;  *rt2 = (acmx / *rt1) * acmn - (b / *rt1) * b; }
  else               { *rt1 = 0.5f * rt; *rt2 = -0.5f * rt; sgn1 = 1; }
  float cs; int sgn2;
  if (df >= 0.f) { cs = df + rt; sgn2 = 1; } else { cs = df - rt; sgn2 = -1; }
  float acs = fabsf(cs);
  if (acs > ab) {
    float ct = -tb / cs;
    *sn1 = 1.f / sqrtf(1.f + ct * ct);
    *cs1 = ct * *sn1;
  } else {
    if (ab == 0.f) { *cs1 = 1.f; *sn1 = 0.f; }
    else {
      float tn = -cs / tb;
      *cs1 = 1.f / sqrtf(1.f + tn * tn);
      *sn1 = tn * *cs1;
    }
  }
  if (sgn1 == sgn2) { float tn = *cs1; *cs1 = -*sn1; *sn1 = tn; }
}

__device__ void eig3_lapack(float a00, float a10, float a11, float a20, float a21, float a22,
                            float vec[3], float eval[3]) {
#pragma clang fp contract(off)
  const float eps    = 5.9604645e-08f;
  const float eps2   = 3.5527137e-15f;
  const float safmin = 1.17549435e-38f;
  const float ssfmax = 3.0744573e18f;
  const float ssfmin = 3.0517578e-05f;

  float d[3], e[2], Z[3][3];
  float tau, v2;

  // ---- ssytd2 'L' ----
  {
    float alpha = a10, xx = a20;
    if (xx == 0.f) {
      tau = 0.f; v2 = 0.f;
      e[0] = alpha;
      d[0] = a00; d[1] = a11; d[2] = a22; e[1] = a21;
    } else {
      float xnorm = fabsf(xx);
      float beta = -copysignf(slapy2f(alpha, xnorm), alpha);
      tau = (beta - alpha) / beta;
      float sc = 1.f / (alpha - beta);
      v2 = xx * sc;
      e[0] = beta;
      float x1 = tau * a11 + tau * (a21 * v2);
      float x2 = tau * a21 + (tau * v2) * a22;
      float dotxv = x1 + x2 * v2;
      float aw = (-0.5f * tau) * dotxv;
      float w1 = x1 + aw;
      float w2 = x2 + aw * v2;
      d[0] = a00;
      d[1] = (a11 - w1) - w1;
      e[1] = (a21 - v2 * w1) - w2;
      d[2] = (a22 - v2 * w2) - w2 * v2;
    }
  }
  Z[0][0] = 1.f; Z[0][1] = 0.f; Z[0][2] = 0.f;
  Z[1][0] = 0.f; Z[1][1] = 1.f; Z[1][2] = 0.f;
  Z[2][0] = 0.f; Z[2][1] = 0.f; Z[2][2] = 1.f;

  int nmaxit = 90, jtot = 0, l1 = 1;
  int l = 0, lsv = 0, lend = 0, lendsv = 0, m = 0, iscale = 0;
  float anorm = 0.f, p = 0.f, g = 0.f, r = 0.f, c = 0.f, s = 0.f, rt1 = 0.f, rt2 = 0.f;
  float cw[2], sw[2];
  cw[0] = cw[1] = sw[0] = sw[1] = 0.f;

L10:
  if (l1 > 3) goto L160;
  if (l1 > 1) e[l1 - 2] = 0.f;
  if (l1 <= 2) {
    for (m = l1; m <= 2; ++m) {
      float tst = fabsf(e[m - 1]);
      if (tst == 0.f) goto L30;
      if (tst <= (sqrtf(fabsf(d[m - 1])) * sqrtf(fabsf(d[m]))) * eps) { e[m - 1] = 0.f; goto L30; }
    }
  }
  m = 3;
L30:
  l = l1; lsv = l; lend = m; lendsv = lend; l1 = m + 1;
  if (lend == l) goto L10;
  anorm = fabsf(d[lend - 1]);
  for (int i = l; i < lend; ++i) {
    anorm = fmaxf(anorm, fabsf(d[i - 1]));
    anorm = fmaxf(anorm, fabsf(e[i - 1]));
  }
  iscale = 0;
  if (anorm == 0.f) goto L10;
  if (anorm > ssfmax) {
    iscale = 1;
    float mul = ssfmax / anorm;
    for (int i = l; i <= lend; ++i) d[i - 1] *= mul;
    for (int i = l; i < lend; ++i) e[i - 1] *= mul;
  } else if (anorm < ssfmin) {
    iscale = 2;
    float mul = ssfmin / anorm;
    for (int i = l; i <= lend; ++i) d[i - 1] *= mul;
    for (int i = l; i < lend; ++i) e[i - 1] *= mul;
  }
  if (fabsf(d[lend - 1]) < fabsf(d[l - 1])) { lend = lsv; l = lendsv; }
  if (lend > l) goto L40; else goto L90;

L40:
  if (l != lend) {
    for (m = l; m <= lend - 1; ++m) {
      float tst = e[m - 1] * e[m - 1];
      if (tst <= (eps2 * fabsf(d[m - 1])) * fabsf(d[m]) + safmin) goto L60;
    }
  }
  m = lend;
L60:
  if (m < lend) e[m - 1] = 0.f;
  p = d[l - 1];
  if (m == l) goto L80;
  if (m == l + 1) {
    slaev2f(d[l - 1], e[l - 1], d[l], &rt1, &rt2, &c, &s);
    for (int i = 0; i < 3; ++i) {
      float t0 = Z[i][l], t1 = Z[i][l - 1];
      Z[i][l]     = c * t0 - s * t1;
      Z[i][l - 1] = s * t0 + c * t1;
    }
    d[l - 1] = rt1; d[l] = rt2; e[l - 1] = 0.f;
    l += 2;
    if (l <= lend) goto L40;
    goto L140;
  }
  if (jtot == nmaxit) goto L140;
  ++jtot;
  g = (d[l] - p) / (2.f * e[l - 1]);
  r = slapy2f(g, 1.f);
  g = d[m - 1] - p + e[l - 1] / (g + copysignf(r, g));
  s = 1.f; c = 1.f; p = 0.f;
  for (int i = m - 1; i >= l; --i) {
    float f = s * e[i - 1];
    float bb = c * e[i - 1];
    slartgf(g, f, &c, &s, &r);
    if (i != m - 1) e[i] = r;
    g = d[i] - p;
    r = (d[i - 1] - g) * s + 2.f * c * bb;
    p = s * r;
    d[i] = g + p;
    g = c * r - bb;
    cw[i - 1] = c; sw[i - 1] = -s;
  }
  {
    int mm = m - l + 1;
    for (int j = mm - 1; j >= 1; --j) {
      float ct = cw[l + j - 2], st = sw[l + j - 2];
      int hi = (l - 1) + j;
      for (int i = 0; i < 3; ++i) {
        float t0 = Z[i][hi], t1 = Z[i][hi - 1];
        Z[i][hi]     = ct * t0 - st * t1;
        Z[i][hi - 1] = st * t0 + ct * t1;
      }
    }
  }
  d[l - 1] = d[l - 1] - p;
  e[l - 1] = g;
  goto L40;
L80:
  d[l - 1] = p;
  ++l;
  if (l <= lend) goto L40;
  goto L140;

L90:
  if (l != lend) {
    for (m = l; m >= lend + 1; --m) {
      float tst = e[m - 2] * e[m - 2];
      if (tst <= (eps2 * fabsf(d[m - 1])) * fabsf(d[m - 2]) + safmin) goto L110;
    }
  }
  m = lend;
L110:
  if (m > lend) e[m - 2] = 0.f;
  p = d[l - 1];
  if (m == l) goto L130;
  if (m == l - 1) {
    slaev2f(d[l - 2], e[l - 2], d[l - 1], &rt1, &rt2, &c, &s);
    for (int i = 0; i < 3; ++i) {
      float t0 = Z[i][l - 1], t1 = Z[i][l - 2];
      Z[i][l - 1] = c * t0 - s * t1;
      Z[i][l - 2] = s * t0 + c * t1;
    }
    d[l - 2] = rt1; d[l - 1] = rt2; e[l - 2] = 0.f;
    l -= 2;
    if (l >= lend) goto L90;
    goto L140;
  }
  if (jtot == nmaxit) goto L140;
  ++jtot;
  g = (d[l - 2] - p) / (2.f * e[l - 2]);
  r = slapy2f(g, 1.f);
  g = d[m - 1] - p + e[l - 2] / (g + copysignf(r, g));
  s = 1.f; c = 1.f; p = 0.f;
  for (int i = m; i <= l - 1; ++i) {
    float f = s * e[i - 1];
    float bb = c * e[i - 1];
    slartgf(g, f, &c, &s, &r);
    if (i != m) e[i - 2] = r;
    g = d[i - 1] - p;
    r = (d[i] - g) * s + 2.f * c * bb;
    p = s * r;
    d[i - 1] = g + p;
    g = c * r - bb;
    cw[i - 1] = c; sw[i - 1] = s;
  }
  {
    int mm = l - m + 1;
    for (int j = 1; j <= mm - 1; ++j) {
      float ct = cw[m + j - 2], st = sw[m + j - 2];
      int lo = (m - 1) + (j - 1);
      for (int i = 0; i < 3; ++i) {
        float t0 = Z[i][lo + 1], t1 = Z[i][lo];
        Z[i][lo + 1] = ct * t0 - st * t1;
        Z[i][lo]     = st * t0 + ct * t1;
      }
    }
  }
  d[l - 1] = d[l - 1] - p;
  e[l - 2] = g;
  goto L90;
L130:
  d[l - 1] = p;
  --l;
  if (l >= lend) goto L90;
  goto L140;

L140:
  if (iscale == 1) {
    float mul = anorm / ssfmax;
    for (int i = lsv; i <= lendsv; ++i) d[i - 1] *= mul;
    for (int i = lsv; i < lendsv; ++i) e[i - 1] *= mul;
  } else if (iscale == 2) {
    float mul = anorm / ssfmin;
    for (int i = lsv; i <= lendsv; ++i) d[i - 1] *= mul;
    for (int i = lsv; i < lendsv; ++i) e[i - 1] *= mul;
  }
  if (jtot < nmaxit) goto L10;
  goto L160;

L160:
  for (int ii = 2; ii <= 3; ++ii) {
    int i0 = ii - 1, k = i0;
    float pp = d[i0 - 1];
    for (int j = ii; j <= 3; ++j) {
      if (d[j - 1] < pp) { k = j; pp = d[j - 1]; }
    }
    if (k != i0) {
      d[k - 1] = d[i0 - 1]; d[i0 - 1] = pp;
      for (int rr2 = 0; rr2 < 3; ++rr2) {
        float t = Z[rr2][i0 - 1]; Z[rr2][i0 - 1] = Z[rr2][k - 1]; Z[rr2][k - 1] = t;
      }
    }
  }
  if (tau != 0.f) {
    for (int j = 0; j < 3; ++j) {
      float wj = Z[1][j] + v2 * Z[2][j];
      Z[1][j] = Z[1][j] - tau * wj;
      Z[2][j] = Z[2][j] - (tau * wj) * v2;
    }
  }
  vec[0] = Z[0][0]; vec[1] = Z[1][0]; vec[2] = Z[2][0];
  eval[0] = d[0]; eval[1] = d[1]; eval[2] = d[2];
}

// ------- branchless sorted top-20 insert, lexicographic (d2, j) key -------
__device__ __forceinline__ void insert20lex(float d2, int j, float bd[KNN], int bi[KNN]) {
  bool c[KNN];
#pragma unroll
  for (int k = 0; k < KNN; ++k)
    c[k] = (d2 < bd[k]) || (d2 == bd[k] && j < bi[k]);
#pragma unroll
  for (int k = KNN - 1; k >= 1; --k) {
    bd[k] = c[k - 1] ? bd[k - 1] : (c[k] ? d2 : bd[k]);
    bi[k] = c[k - 1] ? bi[k - 1] : (c[k] ? j : bi[k]);
  }
  bd[0] = c[0] ? d2 : bd[0];
  bi[0] = c[0] ? j : bi[0];
}

// ---------------- Kernels ----------------

__global__ void prep_kernel(const float* __restrict__ pc, float4* __restrict__ pts4, int total) {
  int i = blockIdx.x * blockDim.x + threadIdx.x;
  if (i < total) {
    float x = pc[i * 3 + 0], y = pc[i * 3 + 1], z = pc[i * 3 + 2];
    pts4[i] = make_float4(x, y, z, fmaf(z, z, fmaf(y, y, x * x)));
  }
}

// Scan kernel with LDS-resident candidates. 32 queries x 8 subs (256 thr).
// Stage planar x/y/z in LDS; pass1 exponent histogram; pass2 pooled collect;
// wave0 lanes 0..31: lexicographic register top-20 -> global lists.
__global__ __launch_bounds__(256, 2) void knn_scan_kernel(const float4* __restrict__ pts4,
                                                          float* __restrict__ knnd,
                                                          int* __restrict__ knni, int total) {
  __shared__ float sx[NPT], sy[NPT], sz[NPT];   // 48 KiB
  __shared__ int   hist[32][QPB];               // 4 KiB
  __shared__ float cbuf[CAPS][QPB];             // 8 KiB
  __shared__ int   ibuf[CAPS][QPB];             // 8 KiB
  __shared__ int   qcnt[QPB];

  const int t = threadIdx.x;
  const int q = t & (QPB - 1);
  const int s = t >> 5;                            // sub 0..7
  const int b = blockIdx.x >> 7;                   // 128 blocks of 32 queries per batch
  const int n = ((blockIdx.x & 127) << 5) + q;
  const int p = (b << 12) + n;
  const float4* __restrict__ P = pts4 + ((size_t)b << 12);

  // ---- stage candidates into LDS (planar) ----
#pragma unroll
  for (int i = 0; i < NPT / 256; ++i) {
    int idx = i * 256 + t;
    float4 v = P[idx];
    sx[idx] = v.x; sy[idx] = v.y; sz[idx] = v.z;
  }
  {
    int* h = &hist[0][0];
#pragma unroll
    for (int k = 0; k < 4; ++k) h[t * 4 + k] = 0;
    if (t < QPB) qcnt[t] = 0;
  }
  const float4 me = P[n];
  const float xi = me.x, yi = me.y, zi = me.z, sqi = me.w;
  __syncthreads();

  const int j0 = s << 9;                           // 512 candidates per sub
  // ---- pass 1: exponent-bin histogram (LDS b128 reads, broadcast) ----
  for (int jj = 0; jj < 512; jj += 8) {
    const int j = j0 + jj;
    float4 x0 = *(const float4*)&sx[j], x1 = *(const float4*)&sx[j + 4];
    float4 y0 = *(const float4*)&sy[j], y1 = *(const float4*)&sy[j + 4];
    float4 z0 = *(const float4*)&sz[j], z1 = *(const float4*)&sz[j + 4];
    float xs[8] = {x0.x, x0.y, x0.z, x0.w, x1.x, x1.y, x1.z, x1.w};
    float ys[8] = {y0.x, y0.y, y0.z, y0.w, y1.x, y1.y, y1.z, y1.w};
    float zs[8] = {z0.x, z0.y, z0.z, z0.w, z1.x, z1.y, z1.z, z1.w};
#pragma unroll
    for (int u = 0; u < 8; ++u) {
      float sqj = fmaf(zs[u], zs[u], fmaf(ys[u], ys[u], xs[u] * xs[u]));
      float dot = fmaf(zi, zs[u], fmaf(yi, ys[u], xi * xs[u]));
      float d2 = fmaf(-2.f, dot, sqi + sqj);
      unsigned bits = __float_as_uint(fmaxf(d2, 0.f));
      int bin = (int)(bits >> 23) - 112;
      bin = max(0, min(31, bin));
      atomicAdd(&hist[bin][q], 1);
    }
  }
  __syncthreads();

  // ---- per-query threshold: upper edge of bin where cumcount >= 20 ----
  float thr;
  {
    int cum = 0, T = 0;
#pragma unroll
    for (int k = 0; k < 32; ++k) {
      cum += hist[k][q];
      T = (cum < KNN) ? (k + 1) : T;
    }
    thr = (T >= 31) ? __builtin_inff() : __uint_as_float((unsigned)(113 + T) << 23);
  }

  // ---- pass 2: pooled collect below threshold ----
  for (int jj = 0; jj < 512; jj += 8) {
    const int j = j0 + jj;
    float4 x0 = *(const float4*)&sx[j], x1 = *(const float4*)&sx[j + 4];
    float4 y0 = *(const float4*)&sy[j], y1 = *(const float4*)&sy[j + 4];
    float4 z0 = *(const float4*)&sz[j], z1 = *(const float4*)&sz[j + 4];
    float xs[8] = {x0.x, x0.y, x0.z, x0.w, x1.x, x1.y, x1.z, x1.w};
    float ys[8] = {y0.x, y0.y, y0.z, y0.w, y1.x, y1.y, y1.z, y1.w};
    float zs[8] = {z0.x, z0.y, z0.z, z0.w, z1.x, z1.y, z1.z, z1.w};
#pragma unroll
    for (int u = 0; u < 8; ++u) {
      float sqj = fmaf(zs[u], zs[u], fmaf(ys[u], ys[u], xs[u] * xs[u]));
      float dot = fmaf(zi, zs[u], fmaf(yi, ys[u], xi * xs[u]));
      float d2 = fmaf(-2.f, dot, sqi + sqj);
      if (d2 < thr) {
        int slot = atomicAdd(&qcnt[q], 1);
        if (slot < CAPS) {
          cbuf[slot][q] = d2;
          ibuf[slot][q] = j + u;
        }
      }
    }
  }
  __syncthreads();

  if (s != 0) return;                              // lanes 0..31 of wave 0 finish

  float bd[KNN]; int bi[KNN];
#pragma unroll
  for (int k = 0; k < KNN; ++k) { bd[k] = __builtin_inff(); bi[k] = 0; }

  const int raw = qcnt[q];
  const int cnt = min(raw, CAPS);
  const bool bad = raw > CAPS;
  for (int i = 0; i < CAPS; ++i) {
    if (__all(i >= cnt)) break;
    if (i < cnt) {
      float d2 = cbuf[i][q]; int jj = ibuf[i][q];
      if (d2 < bd[KNN - 1] || (d2 == bd[KNN - 1] && jj < bi[KNN - 1]))
        insert20lex(d2, jj, bd, bi);
    }
  }
  // exact fallback on collect overflow (correctness guarantee; ~never taken)
  if (__any(bad)) {
    if (bad) {
#pragma unroll
      for (int k = 0; k < KNN; ++k) { bd[k] = __builtin_inff(); bi[k] = 0; }
    }
    for (int j = 0; j < NPT; ++j) {
      float xj = sx[j], yj = sy[j], zj = sz[j];
      float sqj = fmaf(zj, zj, fmaf(yj, yj, xj * xj));
      float dot = fmaf(zi, zj, fmaf(yi, yj, xi * xj));
      float d2 = fmaf(-2.f, dot, sqi + sqj);
      if (bad && (d2 < bd[KNN - 1] || (d2 == bd[KNN - 1] && j < bi[KNN - 1])))
        insert20lex(d2, j, bd, bi);
    }
  }

#pragma unroll
  for (int k = 0; k < KNN; ++k) {
    knnd[k * total + p] = bd[k];
    knni[k * total + p] = bi[k];
  }
}

// One thread per query: gather 20 neighbors, dist feats + covariance + eig.
__global__ __launch_bounds__(256) void feat_kernel(const float4* __restrict__ pts4,
                                                   const float* __restrict__ knnd,
                                                   const int* __restrict__ knni,
                                                   float* __restrict__ feat, int total) {
  const int p = blockIdx.x * 256 + threadIdx.x;
  const int b = p >> 12;
  const float4* __restrict__ P = pts4 + ((size_t)b << 12);
  const float4 me = P[p & 4095];
  const float xi = me.x, yi = me.y, zi = me.z;

  float bd[KNN]; int bi[KNN];
#pragma unroll
  for (int k = 0; k < KNN; ++k) {
    bd[k] = knnd[k * total + p];
    bi[k] = knni[k * total + p];
  }

  float sumd = 0.f, maxd = 0.f, mux = 0.f, muy = 0.f, muz = 0.f;
#pragma unroll
  for (int k = 0; k < KNN; ++k) {
    float dist = sqrtf(fmaxf(bd[k], 0.f) + 1e-12f);
    sumd += dist;
    maxd = fmaxf(maxd, dist);
    float4 nb = P[bi[k]];
    mux += nb.x; muy += nb.y; muz += nb.z;
  }
  float meand = sumd / 20.f;
  mux /= 20.f; muy /= 20.f; muz /= 20.f;

  float cxx = 0.f, cxy = 0.f, cxz = 0.f, cyy = 0.f, cyz = 0.f, czz = 0.f;
#pragma unroll
  for (int k = 0; k < KNN; ++k) {
    float4 nb = P[bi[k]];                          // L1-hot re-gather
    float dx = nb.x - mux, dy = nb.y - muy, dz = nb.z - muz;
    cxx = fmaf(dx, dx, cxx); cxy = fmaf(dx, dy, cxy); cxz = fmaf(dx, dz, cxz);
    cyy = fmaf(dy, dy, cyy); cyz = fmaf(dy, dz, cyz); czz = fmaf(dz, dz, czz);
  }
  cxx /= 20.f; cxy /= 20.f; cxz /= 20.f; cyy /= 20.f; cyz /= 20.f; czz /= 20.f;

  float vec[3], ev[3];
  eig3_lapack(cxx, cxy, cyy, cxz, cyz, czz, vec, ev);
  float curv = ev[0] / (((ev[0] + ev[1]) + ev[2]) + 1e-8f);

  feat[0 * total + p] = xi;
  feat[1 * total + p] = yi;
  feat[2 * total + p] = zi;
  feat[3 * total + p] = vec[0];
  feat[4 * total + p] = vec[1];
  feat[5 * total + p] = vec[2];
  feat[6 * total + p] = curv;
  feat[7 * total + p] = meand;
  feat[8 * total + p] = maxd;
}

// Block: 4 waves. Wave w: points group (w>>1), output channels (w&1)*128.
__global__ __launch_bounds__(256) void mlp_kernel(const float* __restrict__ feat,
    const float* __restrict__ W1, const float* __restrict__ B1,
    const float* __restrict__ W2, const float* __restrict__ B2,
    const float* __restrict__ W3, const float* __restrict__ B3,
    float* __restrict__ out, int total) {
  const int t = threadIdx.x;
  const int l = t & 63;
  const int w = t >> 6;
  const int half = w & 1;                          // channel half
  const int pg = w >> 1;                           // point group
  const int p = blockIdx.x * 128 + pg * 64 + l;

  float f[9];
#pragma unroll
  for (int c = 0; c < 9; ++c) f[c] = feat[c * total + p];

  float h1[64];
#pragma unroll
  for (int o = 0; o < 64; ++o) {
    float acc = B1[o];
#pragma unroll
    for (int i = 0; i < 9; ++i) acc = fmaf(f[i], W1[o * 9 + i], acc);
    h1[o] = fmaxf(acc, 0.f);
  }
  float h2[128];
#pragma unroll
  for (int o = 0; o < 128; ++o) {
    const float* wp = W2 + o * 64;
    float a0 = 0.f, a1 = 0.f, a2 = 0.f, a3 = 0.f;
#pragma unroll
    for (int i = 0; i < 64; i += 4) {
      a0 = fmaf(h1[i    ], wp[i    ], a0);
      a1 = fmaf(h1[i + 1], wp[i + 1], a1);
      a2 = fmaf(h1[i + 2], wp[i + 2], a2);
      a3 = fmaf(h1[i + 3], wp[i + 3], a3);
    }
    h2[o] = fmaxf(B2[o] + ((a0 + a1) + (a2 + a3)), 0.f);
  }

  const int b = p >> 12;
  const int n = p & 4095;
  float* op = out + (size_t)b * (256 * 4096) + n;
  const int obase = half << 7;
#pragma unroll 2
  for (int oo = 0; oo < 128; ++oo) {
    const int o = obase + oo;                      // wave-uniform row of W3
    const float* wp = W3 + o * 128;
    float a0 = 0.f, a1 = 0.f, a2 = 0.f, a3 = 0.f;
#pragma unroll
    for (int i = 0; i < 128; i += 4) {
      a0 = fmaf(h2[i    ], wp[i    ], a0);
      a1 = fmaf(h2[i + 1], wp[i + 1], a1);
      a2 = fmaf(h2[i + 2], wp[i + 2], a2);
      a3 = fmaf(h2[i + 3], wp[i + 3], a3);
    }
    op[(size_t)o * 4096] = B3[o] + ((a0 + a1) + (a2 + a3));
  }
}

extern "C" void kernel_launch(void* const* d_in, const int* in_sizes, int n_in,
                              void* d_out, int out_size, void* d_ws, size_t ws_size,
                              hipStream_t stream) {
  const float* pc = (const float*)d_in[0];
  const float* W1 = (const float*)d_in[1];
  const float* b1 = (const float*)d_in[2];
  const float* W2 = (const float*)d_in[3];
  const float* b2 = (const float*)d_in[4];
  const float* W3 = (const float*)d_in[5];
  const float* b3 = (const float*)d_in[6];
  // d_in[7] = vis_mask (all ones) -- unused, matches reference semantics

  const int total = in_sizes[0] / 3;               // B*N = 32768
  float4* pts4 = (float4*)d_ws;
  float* feat = (float*)((char*)d_ws + (size_t)total * sizeof(float4));
  float* outp = (float*)d_out;
  // Stage top-20 lists in d_out (5.2 MB of 32 MB), overwritten by MLP later.
  float* knnd = outp;
  int*   knni = (int*)(outp + (size_t)KNN * total);

  prep_kernel<<<(total + 255) / 256, 256, 0, stream>>>(pc, pts4, total);
  knn_scan_kernel<<<total / QPB, 256, 0, stream>>>(pts4, knnd, knni, total);
  feat_kernel<<<total / 256, 256, 0, stream>>>(pts4, knnd, knni, feat, total);
  mlp_kernel<<<total / 128, 256, 0, stream>>>(feat, W1, b1, W2, b2, W3, b3, outp, total);
}

// Round 6
// 1180.140 us; speedup vs baseline: 1.6586x; 1.6586x over previous
//
#include <hip/hip_runtime.h>
#include <math.h>

// ============================================================================
// GeometricModule: KNN(20) -> PCA normal/curvature (LAPACK-replica eigh) ->
// local dist feats -> per-point MLP 9->64->128->256, out (B,256,N) f32.
//
// R6: kill the fallback storm. R4/R5's regression = pooled-collect overflow
//     (CAPS 56/64 < Poisson(54) tail) -> whole-wave serial 4096 rescan on
//     most waves. CAPS=128 (P_overflow ~1e-30). Scan reads candidates from
//     global (L2-hot, 97% hit in counters), LDS=36.6KB -> 4 blocks/CU.
//     mlp: 4-way channel split (512 blocks). feat: 64-thr x 512 blocks.
//     Eig path + selection semantics byte-identical to R1-R5 (all passed).
// ============================================================================

#define LARTG_NEW 1
#define NPT 4096
#define KNN 20
#define CAPS 128  // pooled per-query collect capacity (Poisson(54) -> never)
#define QPB 32    // queries per scan block

// ---------------- LAPACK f32 helper replicas ----------------

__device__ __forceinline__ float slapy2f(float x, float y) {
#pragma clang fp contract(off)
  float xa = fabsf(x), ya = fabsf(y);
  float w = fmaxf(xa, ya);
  float z = fminf(xa, ya);
  if (z == 0.f) return w;
  float q = z / w;
  return w * sqrtf(1.f + q * q);
}

__device__ __forceinline__ void slartgf(float f, float g, float* cs, float* sn, float* rr) {
#pragma clang fp contract(off)
#if LARTG_NEW
  const float safmin = 1.17549435e-38f;
  const float safmax = 8.5070592e37f;
  const float rtmin  = 1.0842022e-19f;
  const float rtmax  = 6.5221643e18f;
  float f1 = fabsf(f), g1 = fabsf(g);
  if (g == 0.f) { *cs = 1.f; *sn = 0.f; *rr = f; }
  else if (f == 0.f) { *cs = 0.f; *sn = copysignf(1.f, g); *rr = g1; }
  else {
    if (f1 > rtmin && f1 < rtmax && g1 > rtmin && g1 < rtmax) {
      float dd = sqrtf(f * f + g * g);
      *cs = f1 / dd;
      float r = copysignf(dd, f);
      *sn = g / r;
      *rr = r;
    } else {
      float u = fminf(safmax, fmaxf(safmin, fmaxf(f1, g1)));
      float fs = f / u, gs = g / u;
      float dd = sqrtf(fs * fs + gs * gs);
      *cs = fabsf(fs) / dd;
      float r = copysignf(dd, f);
      *sn = gs / r;
      *rr = r * u;
    }
  }
#else
  if (g == 0.f) { *cs = 1.f; *sn = 0.f; *rr = f; }
  else if (f == 0.f) { *cs = 0.f; *sn = 1.f; *rr = g; }
  else {
    float r = sqrtf(f * f + g * g);
    float c = f / r, s = g / r;
    if (fabsf(f) > fabsf(g) && c < 0.f) { c = -c; s = -s; r = -r; }
    *cs = c; *sn = s; *rr = r;
  }
#endif
}

__device__ __forceinline__ void slaev2f(float a, float b, float c,
                                        float* rt1, float* rt2, float* cs1, float* sn1) {
#pragma clang fp contract(off)
  float sm = a + c, df = a - c, adf = fabsf(df);
  float tb = b + b, ab = fabsf(tb);
  float acmx, acmn;
  if (fabsf(a) > fabsf(c)) { acmx = a; acmn = c; } else { acmx = c; acmn = a; }
  float rt;
  if (adf > ab)      { float t = ab / adf; rt = adf * sqrtf(1.f + t * t); }
  else if (adf < ab) { float t = adf / ab; rt = ab * sqrtf(1.f + t * t); }
  else               { rt = ab * sqrtf(2.f); }
  int sgn1;
  if (sm < 0.f)      { *rt1 = 0.5f * (sm - rt); sgn1 = -1; *rt2 = (acmx / *rt1) * acmn - (b / *rt1) * b; }
  else if (sm > 0.f) { *rt1 = 0.5f * (sm + rt); sgn1 = 1;  *rt2 = (acmx / *rt1) * acmn - (b / *rt1) * b; }
  else               { *rt1 = 0.5f * rt; *rt2 = -0.5f * rt; sgn1 = 1; }
  float cs; int sgn2;
  if (df >= 0.f) { cs = df + rt; sgn2 = 1; } else { cs = df - rt; sgn2 = -1; }
  float acs = fabsf(cs);
  if (acs > ab) {
    float ct = -tb / cs;
    *sn1 = 1.f / sqrtf(1.f + ct * ct);
    *cs1 = ct * *sn1;
  } else {
    if (ab == 0.f) { *cs1 = 1.f; *sn1 = 0.f; }
    else {
      float tn = -cs / tb;
      *cs1 = 1.f / sqrtf(1.f + tn * tn);
      *sn1 = tn * *cs1;
    }
  }
  if (sgn1 == sgn2) { float tn = *cs1; *cs1 = -*sn1; *sn1 = tn; }
}

__device__ void eig3_lapack(float a00, float a10, float a11, float a20, float a21, float a22,
                            float vec[3], float eval[3]) {
#pragma clang fp contract(off)
  const float eps    = 5.9604645e-08f;
  const float eps2   = 3.5527137e-15f;
  const float safmin = 1.17549435e-38f;
  const float ssfmax = 3.0744573e18f;
  const float ssfmin = 3.0517578e-05f;

  float d[3], e[2], Z[3][3];
  float tau, v2;

  // ---- ssytd2 'L' ----
  {
    float alpha = a10, xx = a20;
    if (xx == 0.f) {
      tau = 0.f; v2 = 0.f;
      e[0] = alpha;
      d[0] = a00; d[1] = a11; d[2] = a22; e[1] = a21;
    } else {
      float xnorm = fabsf(xx);
      float beta = -copysignf(slapy2f(alpha, xnorm), alpha);
      tau = (beta - alpha) / beta;
      float sc = 1.f / (alpha - beta);
      v2 = xx * sc;
      e[0] = beta;
      float x1 = tau * a11 + tau * (a21 * v2);
      float x2 = tau * a21 + (tau * v2) * a22;
      float dotxv = x1 + x2 * v2;
      float aw = (-0.5f * tau) * dotxv;
      float w1 = x1 + aw;
      float w2 = x2 + aw * v2;
      d[0] = a00;
      d[1] = (a11 - w1) - w1;
      e[1] = (a21 - v2 * w1) - w2;
      d[2] = (a22 - v2 * w2) - w2 * v2;
    }
  }
  Z[0][0] = 1.f; Z[0][1] = 0.f; Z[0][2] = 0.f;
  Z[1][0] = 0.f; Z[1][1] = 1.f; Z[1][2] = 0.f;
  Z[2][0] = 0.f; Z[2][1] = 0.f; Z[2][2] = 1.f;

  int nmaxit = 90, jtot = 0, l1 = 1;
  int l = 0, lsv = 0, lend = 0, lendsv = 0, m = 0, iscale = 0;
  float anorm = 0.f, p = 0.f, g = 0.f, r = 0.f, c = 0.f, s = 0.f, rt1 = 0.f, rt2 = 0.f;
  float cw[2], sw[2];
  cw[0] = cw[1] = sw[0] = sw[1] = 0.f;

L10:
  if (l1 > 3) goto L160;
  if (l1 > 1) e[l1 - 2] = 0.f;
  if (l1 <= 2) {
    for (m = l1; m <= 2; ++m) {
      float tst = fabsf(e[m - 1]);
      if (tst == 0.f) goto L30;
      if (tst <= (sqrtf(fabsf(d[m - 1])) * sqrtf(fabsf(d[m]))) * eps) { e[m - 1] = 0.f; goto L30; }
    }
  }
  m = 3;
L30:
  l = l1; lsv = l; lend = m; lendsv = lend; l1 = m + 1;
  if (lend == l) goto L10;
  anorm = fabsf(d[lend - 1]);
  for (int i = l; i < lend; ++i) {
    anorm = fmaxf(anorm, fabsf(d[i - 1]));
    anorm = fmaxf(anorm, fabsf(e[i - 1]));
  }
  iscale = 0;
  if (anorm == 0.f) goto L10;
  if (anorm > ssfmax) {
    iscale = 1;
    float mul = ssfmax / anorm;
    for (int i = l; i <= lend; ++i) d[i - 1] *= mul;
    for (int i = l; i < lend; ++i) e[i - 1] *= mul;
  } else if (anorm < ssfmin) {
    iscale = 2;
    float mul = ssfmin / anorm;
    for (int i = l; i <= lend; ++i) d[i - 1] *= mul;
    for (int i = l; i < lend; ++i) e[i - 1] *= mul;
  }
  if (fabsf(d[lend - 1]) < fabsf(d[l - 1])) { lend = lsv; l = lendsv; }
  if (lend > l) goto L40; else goto L90;

L40:
  if (l != lend) {
    for (m = l; m <= lend - 1; ++m) {
      float tst = e[m - 1] * e[m - 1];
      if (tst <= (eps2 * fabsf(d[m - 1])) * fabsf(d[m]) + safmin) goto L60;
    }
  }
  m = lend;
L60:
  if (m < lend) e[m - 1] = 0.f;
  p = d[l - 1];
  if (m == l) goto L80;
  if (m == l + 1) {
    slaev2f(d[l - 1], e[l - 1], d[l], &rt1, &rt2, &c, &s);
    for (int i = 0; i < 3; ++i) {
      float t0 = Z[i][l], t1 = Z[i][l - 1];
      Z[i][l]     = c * t0 - s * t1;
      Z[i][l - 1] = s * t0 + c * t1;
    }
    d[l - 1] = rt1; d[l] = rt2; e[l - 1] = 0.f;
    l += 2;
    if (l <= lend) goto L40;
    goto L140;
  }
  if (jtot == nmaxit) goto L140;
  ++jtot;
  g = (d[l] - p) / (2.f * e[l - 1]);
  r = slapy2f(g, 1.f);
  g = d[m - 1] - p + e[l - 1] / (g + copysignf(r, g));
  s = 1.f; c = 1.f; p = 0.f;
  for (int i = m - 1; i >= l; --i) {
    float f = s * e[i - 1];
    float bb = c * e[i - 1];
    slartgf(g, f, &c, &s, &r);
    if (i != m - 1) e[i] = r;
    g = d[i] - p;
    r = (d[i - 1] - g) * s + 2.f * c * bb;
    p = s * r;
    d[i] = g + p;
    g = c * r - bb;
    cw[i - 1] = c; sw[i - 1] = -s;
  }
  {
    int mm = m - l + 1;
    for (int j = mm - 1; j >= 1; --j) {
      float ct = cw[l + j - 2], st = sw[l + j - 2];
      int hi = (l - 1) + j;
      for (int i = 0; i < 3; ++i) {
        float t0 = Z[i][hi], t1 = Z[i][hi - 1];
        Z[i][hi]     = ct * t0 - st * t1;
        Z[i][hi - 1] = st * t0 + ct * t1;
      }
    }
  }
  d[l - 1] = d[l - 1] - p;
  e[l - 1] = g;
  goto L40;
L80:
  d[l - 1] = p;
  ++l;
  if (l <= lend) goto L40;
  goto L140;

L90:
  if (l != lend) {
    for (m = l; m >= lend + 1; --m) {
      float tst = e[m - 2] * e[m - 2];
      if (tst <= (eps2 * fabsf(d[m - 1])) * fabsf(d[m - 2]) + safmin) goto L110;
    }
  }
  m = lend;
L110:
  if (m > lend) e[m - 2] = 0.f;
  p = d[l - 1];
  if (m == l) goto L130;
  if (m == l - 1) {
    slaev2f(d[l - 2], e[l - 2], d[l - 1], &rt1, &rt2, &c, &s);
    for (int i = 0; i < 3; ++i) {
      float t0 = Z[i][l - 1], t1 = Z[i][l - 2];
      Z[i][l - 1] = c * t0 - s * t1;
      Z[i][l - 2] = s * t0 + c * t1;
    }
    d[l - 2] = rt1; d[l - 1] = rt2; e[l - 2] = 0.f;
    l -= 2;
    if (l >= lend) goto L90;
    goto L140;
  }
  if (jtot == nmaxit) goto L140;
  ++jtot;
  g = (d[l - 2] - p) / (2.f * e[l - 2]);
  r = slapy2f(g, 1.f);
  g = d[m - 1] - p + e[l - 2] / (g + copysignf(r, g));
  s = 1.f; c = 1.f; p = 0.f;
  for (int i = m; i <= l - 1; ++i) {
    float f = s * e[i - 1];
    float bb = c * e[i - 1];
    slartgf(g, f, &c, &s, &r);
    if (i != m) e[i - 2] = r;
    g = d[i - 1] - p;
    r = (d[i] - g) * s + 2.f * c * bb;
    p = s * r;
    d[i - 1] = g + p;
    g = c * r - bb;
    cw[i - 1] = c; sw[i - 1] = s;
  }
  {
    int mm = l - m + 1;
    for (int j = 1; j <= mm - 1; ++j) {
      float ct = cw[m + j - 2], st = sw[m + j - 2];
      int lo = (m - 1) + (j - 1);
      for (int i = 0; i < 3; ++i) {
        float t0 = Z[i][lo + 1], t1 = Z[i][lo];
        Z[i][lo + 1] = ct * t0 - st * t1;
        Z[i][lo]     = st * t0 + ct * t1;
      }
    }
  }
  d[l - 1] = d[l - 1] - p;
  e[l - 2] = g;
  goto L90;
L130:
  d[l - 1] = p;
  --l;
  if (l >= lend) goto L90;
  goto L140;

L140:
  if (iscale == 1) {
    float mul = anorm / ssfmax;
    for (int i = lsv; i <= lendsv; ++i) d[i - 1] *= mul;
    for (int i = lsv; i < lendsv; ++i) e[i - 1] *= mul;
  } else if (iscale == 2) {
    float mul = anorm / ssfmin;
    for (int i = lsv; i <= lendsv; ++i) d[i - 1] *= mul;
    for (int i = lsv; i < lendsv; ++i) e[i - 1] *= mul;
  }
  if (jtot < nmaxit) goto L10;
  goto L160;

L160:
  for (int ii = 2; ii <= 3; ++ii) {
    int i0 = ii - 1, k = i0;
    float pp = d[i0 - 1];
    for (int j = ii; j <= 3; ++j) {
      if (d[j - 1] < pp) { k = j; pp = d[j - 1]; }
    }
    if (k != i0) {
      d[k - 1] = d[i0 - 1]; d[i0 - 1] = pp;
      for (int rr2 = 0; rr2 < 3; ++rr2) {
        float t = Z[rr2][i0 - 1]; Z[rr2][i0 - 1] = Z[rr2][k - 1]; Z[rr2][k - 1] = t;
      }
    }
  }
  if (tau != 0.f) {
    for (int j = 0; j < 3; ++j) {
      float wj = Z[1][j] + v2 * Z[2][j];
      Z[1][j] = Z[1][j] - tau * wj;
      Z[2][j] = Z[2][j] - (tau * wj) * v2;
    }
  }
  vec[0] = Z[0][0]; vec[1] = Z[1][0]; vec[2] = Z[2][0];
  eval[0] = d[0]; eval[1] = d[1]; eval[2] = d[2];
}

// ------- branchless sorted top-20 insert, lexicographic (d2, j) key -------
__device__ __forceinline__ void insert20lex(float d2, int j, float bd[KNN], int bi[KNN]) {
  bool c[KNN];
#pragma unroll
  for (int k = 0; k < KNN; ++k)
    c[k] = (d2 < bd[k]) || (d2 == bd[k] && j < bi[k]);
#pragma unroll
  for (int k = KNN - 1; k >= 1; --k) {
    bd[k] = c[k - 1] ? bd[k - 1] : (c[k] ? d2 : bd[k]);
    bi[k] = c[k - 1] ? bi[k - 1] : (c[k] ? j : bi[k]);
  }
  bd[0] = c[0] ? d2 : bd[0];
  bi[0] = c[0] ? j : bi[0];
}

// ---------------- Kernels ----------------

__global__ void prep_kernel(const float* __restrict__ pc, float4* __restrict__ pts4, int total) {
  int i = blockIdx.x * blockDim.x + threadIdx.x;
  if (i < total) {
    float x = pc[i * 3 + 0], y = pc[i * 3 + 1], z = pc[i * 3 + 2];
    pts4[i] = make_float4(x, y, z, fmaf(z, z, fmaf(y, y, x * x)));
  }
}

// Scan kernel: 32 queries x 8 subs (256 thr). Candidates from global (L2-hot).
// Pass1: exponent histogram. Pass2: pooled collect, CAPS=128 (overflow ~never).
// Wave0 lanes 0..31: lexicographic register top-20 -> global lists.
__global__ __launch_bounds__(256) void knn_scan_kernel(const float4* __restrict__ pts4,
                                                       float* __restrict__ knnd,
                                                       int* __restrict__ knni, int total) {
  __shared__ int   hist[32][QPB];     // 4 KiB
  __shared__ float cbuf[CAPS][QPB];   // 16 KiB
  __shared__ int   ibuf[CAPS][QPB];   // 16 KiB
  __shared__ int   qcnt[QPB];

  const int t = threadIdx.x;
  const int q = t & (QPB - 1);
  const int s = t >> 5;                            // sub 0..7
  const int b = blockIdx.x >> 7;                   // 128 blocks of 32 queries per batch
  const int n = ((blockIdx.x & 127) << 5) + q;
  const int p = (b << 12) + n;
  const float4* __restrict__ P = pts4 + ((size_t)b << 12);
  const float4 me = P[n];
  const float xi = me.x, yi = me.y, zi = me.z, sqi = me.w;

  {
    int* h = &hist[0][0];
#pragma unroll
    for (int k = 0; k < 4; ++k) h[t * 4 + k] = 0;
    if (t < QPB) qcnt[t] = 0;
  }
  __syncthreads();

  const int j0 = s << 9;                           // 512 candidates per sub
  // ---- pass 1: exponent-bin histogram (4-wide load batches for ILP) ----
  for (int jj = 0; jj < 512; jj += 4) {
    float4 cc[4];
#pragma unroll
    for (int u = 0; u < 4; ++u) cc[u] = P[j0 + jj + u];
#pragma unroll
    for (int u = 0; u < 4; ++u) {
      float dot = fmaf(zi, cc[u].z, fmaf(yi, cc[u].y, xi * cc[u].x));
      float d2 = fmaf(-2.f, dot, sqi + cc[u].w);
      unsigned bits = __float_as_uint(fmaxf(d2, 0.f));
      int bin = (int)(bits >> 23) - 112;
      bin = max(0, min(31, bin));
      atomicAdd(&hist[bin][q], 1);
    }
  }
  __syncthreads();

  // ---- per-query threshold: upper edge of bin where cumcount >= 20 ----
  float thr;
  {
    int cum = 0, T = 0;
#pragma unroll
    for (int k = 0; k < 32; ++k) {
      cum += hist[k][q];
      T = (cum < KNN) ? (k + 1) : T;
    }
    thr = (T >= 31) ? __builtin_inff() : __uint_as_float((unsigned)(113 + T) << 23);
  }

  // ---- pass 2: pooled collect below threshold ----
  for (int jj = 0; jj < 512; jj += 4) {
    float4 cc[4];
#pragma unroll
    for (int u = 0; u < 4; ++u) cc[u] = P[j0 + jj + u];
#pragma unroll
    for (int u = 0; u < 4; ++u) {
      float dot = fmaf(zi, cc[u].z, fmaf(yi, cc[u].y, xi * cc[u].x));
      float d2 = fmaf(-2.f, dot, sqi + cc[u].w);
      if (d2 < thr) {
        int slot = atomicAdd(&qcnt[q], 1);
        if (slot < CAPS) {
          cbuf[slot][q] = d2;
          ibuf[slot][q] = j0 + jj + u;
        }
      }
    }
  }
  __syncthreads();

  if (s != 0) return;                              // lanes 0..31 of wave 0 finish

  float bd[KNN]; int bi[KNN];
#pragma unroll
  for (int k = 0; k < KNN; ++k) { bd[k] = __builtin_inff(); bi[k] = 0; }

  const int raw = qcnt[q];
  const int cnt = min(raw, CAPS);
  const bool bad = raw > CAPS;
  for (int i = 0; i < CAPS; ++i) {
    if (__all(i >= cnt)) break;
    if (i < cnt) {
      float d2 = cbuf[i][q]; int jj = ibuf[i][q];
      if (d2 < bd[KNN - 1] || (d2 == bd[KNN - 1] && jj < bi[KNN - 1]))
        insert20lex(d2, jj, bd, bi);
    }
  }
  // exact fallback on collect overflow (correctness guarantee; P ~ 1e-30)
  if (__any(bad)) {
    if (bad) {
#pragma unroll
      for (int k = 0; k < KNN; ++k) { bd[k] = __builtin_inff(); bi[k] = 0; }
    }
    for (int j = 0; j < NPT; ++j) {
      float4 cj = P[j];
      float dot = fmaf(zi, cj.z, fmaf(yi, cj.y, xi * cj.x));
      float d2 = fmaf(-2.f, dot, sqi + cj.w);
      if (bad && (d2 < bd[KNN - 1] || (d2 == bd[KNN - 1] && j < bi[KNN - 1])))
        insert20lex(d2, j, bd, bi);
    }
  }

#pragma unroll
  for (int k = 0; k < KNN; ++k) {
    knnd[k * total + p] = bd[k];
    knni[k * total + p] = bi[k];
  }
}

// One thread per query: gather 20 neighbors, dist feats + covariance + eig.
// 64-thread blocks x 512 so every CU gets eig work.
__global__ __launch_bounds__(64) void feat_kernel(const float4* __restrict__ pts4,
                                                  const float* __restrict__ knnd,
                                                  const int* __restrict__ knni,
                                                  float* __restrict__ feat, int total) {
  const int p = blockIdx.x * 64 + threadIdx.x;
  const int b = p >> 12;
  const float4* __restrict__ P = pts4 + ((size_t)b << 12);
  const float4 me = P[p & 4095];
  const float xi = me.x, yi = me.y, zi = me.z;

  float bd[KNN]; int bi[KNN];
#pragma unroll
  for (int k = 0; k < KNN; ++k) {
    bd[k] = knnd[k * total + p];
    bi[k] = knni[k * total + p];
  }

  float sumd = 0.f, maxd = 0.f, mux = 0.f, muy = 0.f, muz = 0.f;
#pragma unroll
  for (int k = 0; k < KNN; ++k) {
    float dist = sqrtf(fmaxf(bd[k], 0.f) + 1e-12f);
    sumd += dist;
    maxd = fmaxf(maxd, dist);
    float4 nb = P[bi[k]];
    mux += nb.x; muy += nb.y; muz += nb.z;
  }
  float meand = sumd / 20.f;
  mux /= 20.f; muy /= 20.f; muz /= 20.f;

  float cxx = 0.f, cxy = 0.f, cxz = 0.f, cyy = 0.f, cyz = 0.f, czz = 0.f;
#pragma unroll
  for (int k = 0; k < KNN; ++k) {
    float4 nb = P[bi[k]];                          // L1-hot re-gather
    float dx = nb.x - mux, dy = nb.y - muy, dz = nb.z - muz;
    cxx = fmaf(dx, dx, cxx); cxy = fmaf(dx, dy, cxy); cxz = fmaf(dx, dz, cxz);
    cyy = fmaf(dy, dy, cyy); cyz = fmaf(dy, dz, cyz); czz = fmaf(dz, dz, czz);
  }
  cxx /= 20.f; cxy /= 20.f; cxz /= 20.f; cyy /= 20.f; cyz /= 20.f; czz /= 20.f;

  float vec[3], ev[3];
  eig3_lapack(cxx, cxy, cyy, cxz, cyz, czz, vec, ev);
  float curv = ev[0] / (((ev[0] + ev[1]) + ev[2]) + 1e-8f);

  feat[0 * total + p] = xi;
  feat[1 * total + p] = yi;
  feat[2 * total + p] = zi;
  feat[3 * total + p] = vec[0];
  feat[4 * total + p] = vec[1];
  feat[5 * total + p] = vec[2];
  feat[6 * total + p] = curv;
  feat[7 * total + p] = meand;
  feat[8 * total + p] = maxd;
}

// Block: 64 points x 4 waves. Wave w computes h1/h2 for its lane's point
// (redundant x4, weight addresses wave-uniform -> s_loads) and emits its
// 64 of the 256 output channels. 512 blocks -> 2 blocks/CU resident.
__global__ __launch_bounds__(256) void mlp_kernel(const float* __restrict__ feat,
    const float* __restrict__ W1, const float* __restrict__ B1,
    const float* __restrict__ W2, const float* __restrict__ B2,
    const float* __restrict__ W3, const float* __restrict__ B3,
    float* __restrict__ out, int total) {
  const int t = threadIdx.x;
  const int l = t & 63;
  const int w = t >> 6;                            // channel quarter 0..3
  const int p = blockIdx.x * 64 + l;

  float f[9];
#pragma unroll
  for (int c = 0; c < 9; ++c) f[c] = feat[c * total + p];

  float h1[64];
#pragma unroll
  for (int o = 0; o < 64; ++o) {
    float acc = B1[o];
#pragma unroll
    for (int i = 0; i < 9; ++i) acc = fmaf(f[i], W1[o * 9 + i], acc);
    h1[o] = fmaxf(acc, 0.f);
  }
  float h2[128];
#pragma unroll
  for (int o = 0; o < 128; ++o) {
    const float* wp = W2 + o * 64;
    float a0 = 0.f, a1 = 0.f, a2 = 0.f, a3 = 0.f;
#pragma unroll
    for (int i = 0; i < 64; i += 4) {
      a0 = fmaf(h1[i    ], wp[i    ], a0);
      a1 = fmaf(h1[i + 1], wp[i + 1], a1);
      a2 = fmaf(h1[i + 2], wp[i + 2], a2);
      a3 = fmaf(h1[i + 3], wp[i + 3], a3);
    }
    h2[o] = fmaxf(B2[o] + ((a0 + a1) + (a2 + a3)), 0.f);
  }

  const int b = p >> 12;
  const int n = p & 4095;
  float* op = out + (size_t)b * (256 * 4096) + n;
  const int obase = w << 6;
#pragma unroll 2
  for (int oo = 0; oo < 64; ++oo) {
    const int o = obase + oo;                      // wave-uniform row of W3
    const float* wp = W3 + o * 128;
    float a0 = 0.f, a1 = 0.f, a2 = 0.f, a3 = 0.f;
#pragma unroll
    for (int i = 0; i < 128; i += 4) {
      a0 = fmaf(h2[i    ], wp[i    ], a0);
      a1 = fmaf(h2[i + 1], wp[i + 1], a1);
      a2 = fmaf(h2[i + 2], wp[i + 2], a2);
      a3 = fmaf(h2[i + 3], wp[i + 3], a3);
    }
    op[(size_t)o * 4096] = B3[o] + ((a0 + a1) + (a2 + a3));
  }
}

extern "C" void kernel_launch(void* const* d_in, const int* in_sizes, int n_in,
                              void* d_out, int out_size, void* d_ws, size_t ws_size,
                              hipStream_t stream) {
  const float* pc = (const float*)d_in[0];
  const float* W1 = (const float*)d_in[1];
  const float* b1 = (const float*)d_in[2];
  const float* W2 = (const float*)d_in[3];
  const float* b2 = (const float*)d_in[4];
  const float* W3 = (const float*)d_in[5];
  const float* b3 = (const float*)d_in[6];
  // d_in[7] = vis_mask (all ones) -- unused, matches reference semantics

  const int total = in_sizes[0] / 3;               // B*N = 32768
  float4* pts4 = (float4*)d_ws;
  float* feat = (float*)((char*)d_ws + (size_t)total * sizeof(float4));
  float* outp = (float*)d_out;
  // Stage top-20 lists in d_out (10.5 MB of 32 MB), overwritten by MLP later.
  float* knnd = outp;
  int*   knni = (int*)(outp + (size_t)KNN * total);

  prep_kernel<<<(total + 255) / 256, 256, 0, stream>>>(pc, pts4, total);
  knn_scan_kernel<<<total / QPB, 256, 0, stream>>>(pts4, knnd, knni, total);
  feat_kernel<<<total / 64, 64, 0, stream>>>(pts4, knnd, knni, feat, total);
  mlp_kernel<<<total / 64, 256, 0, stream>>>(feat, W1, b1, W2, b2, W3, b3, outp, total);
}

// Round 7
// 671.822 us; speedup vs baseline: 2.9135x; 1.7566x over previous
//
#include <hip/hip_runtime.h>
#include <math.h>

// ============================================================================
// GeometricModule: KNN(20) -> PCA normal/curvature (LAPACK-replica eigh) ->
// local dist feats -> per-point MLP 9->64->128->256, out (B,256,N) f32.
//
// R7: atomic-free pass1. R2..R6 all shared a ~850us scan floor = one LDS
//     atomic per candidate (2.68e8 lane-RMWs). Replaced histogram with
//     branchless register top-3 per sub; thr = max of the 8 sub-top3 thirds.
//     Guarantees >=23 collected (distinct values); raw<20 OR raw>CAPS(192)
//     -> exact fallback. mlp: readfirstlane W3 row (force s_loads).
//     Eig path + selection semantics byte-identical to R1-R6 (all passed).
// ============================================================================

#define LARTG_NEW 1
#define NPT 4096
#define KNN 20
#define CAPS 192  // pooled per-query collect capacity (E~52, P(>192)~0)
#define QPB 32    // queries per scan block
#define SUBS 8

// ---------------- LAPACK f32 helper replicas ----------------

__device__ __forceinline__ float slapy2f(float x, float y) {
#pragma clang fp contract(off)
  float xa = fabsf(x), ya = fabsf(y);
  float w = fmaxf(xa, ya);
  float z = fminf(xa, ya);
  if (z == 0.f) return w;
  float q = z / w;
  return w * sqrtf(1.f + q * q);
}

__device__ __forceinline__ void slartgf(float f, float g, float* cs, float* sn, float* rr) {
#pragma clang fp contract(off)
#if LARTG_NEW
  const float safmin = 1.17549435e-38f;
  const float safmax = 8.5070592e37f;
  const float rtmin  = 1.0842022e-19f;
  const float rtmax  = 6.5221643e18f;
  float f1 = fabsf(f), g1 = fabsf(g);
  if (g == 0.f) { *cs = 1.f; *sn = 0.f; *rr = f; }
  else if (f == 0.f) { *cs = 0.f; *sn = copysignf(1.f, g); *rr = g1; }
  else {
    if (f1 > rtmin && f1 < rtmax && g1 > rtmin && g1 < rtmax) {
      float dd = sqrtf(f * f + g * g);
      *cs = f1 / dd;
      float r = copysignf(dd, f);
      *sn = g / r;
      *rr = r;
    } else {
      float u = fminf(safmax, fmaxf(safmin, fmaxf(f1, g1)));
      float fs = f / u, gs = g / u;
      float dd = sqrtf(fs * fs + gs * gs);
      *cs = fabsf(fs) / dd;
      float r = copysignf(dd, f);
      *sn = gs / r;
      *rr = r * u;
    }
  }
#else
  if (g == 0.f) { *cs = 1.f; *sn = 0.f; *rr = f; }
  else if (f == 0.f) { *cs = 0.f; *sn = 1.f; *rr = g; }
  else {
    float r = sqrtf(f * f + g * g);
    float c = f / r, s = g / r;
    if (fabsf(f) > fabsf(g) && c < 0.f) { c = -c; s = -s; r = -r; }
    *cs = c; *sn = s; *rr = r;
  }
#endif
}

__device__ __forceinline__ void slaev2f(float a, float b, float c,
                                        float* rt1, float* rt2, float* cs1, float* sn1) {
#pragma clang fp contract(off)
  float sm = a + c, df = a - c, adf = fabsf(df);
  float tb = b + b, ab = fabsf(tb);
  float acmx, acmn;
  if (fabsf(a) > fabsf(c)) { acmx = a; acmn = c; } else { acmx = c; acmn = a; }
  float rt;
  if (adf > ab)      { float t = ab / adf; rt = adf * sqrtf(1.f + t * t); }
  else if (adf < ab) { float t = adf / ab; rt = ab * sqrtf(1.f + t * t); }
  else               { rt = ab * sqrtf(2.f); }
  int sgn1;
  if (sm < 0.f)      { *rt1 = 0.5f * (sm - rt); sgn1 = -1; *rt2 = (acmx / *rt1) * acmn - (b / *rt1) * b; }
  else if (sm > 0.f) { *rt1 = 0.5f * (sm + rt); sgn1 = 1;  *rt2 = (acmx / *rt1) * acmn - (b / *rt1) * b; }
  else               { *rt1 = 0.5f * rt; *rt2 = -0.5f * rt; sgn1 = 1; }
  float cs; int sgn2;
  if (df >= 0.f) { cs = df + rt; sgn2 = 1; } else { cs = df - rt; sgn2 = -1; }
  float acs = fabsf(cs);
  if (acs > ab) {
    float ct = -tb / cs;
    *sn1 = 1.f / sqrtf(1.f + ct * ct);
    *cs1 = ct * *sn1;
  } else {
    if (ab == 0.f) { *cs1 = 1.f; *sn1 = 0.f; }
    else {
      float tn = -cs / tb;
      *cs1 = 1.f / sqrtf(1.f + tn * tn);
      *sn1 = tn * *cs1;
    }
  }
  if (sgn1 == sgn2) { float tn = *cs1; *cs1 = -*sn1; *sn1 = tn; }
}

__device__ void eig3_lapack(float a00, float a10, float a11, float a20, float a21, float a22,
                            float vec[3], float eval[3]) {
#pragma clang fp contract(off)
  const float eps    = 5.9604645e-08f;
  const float eps2   = 3.5527137e-15f;
  const float safmin = 1.17549435e-38f;
  const float ssfmax = 3.0744573e18f;
  const float ssfmin = 3.0517578e-05f;

  float d[3], e[2], Z[3][3];
  float tau, v2;

  // ---- ssytd2 'L' ----
  {
    float alpha = a10, xx = a20;
    if (xx == 0.f) {
      tau = 0.f; v2 = 0.f;
      e[0] = alpha;
      d[0] = a00; d[1] = a11; d[2] = a22; e[1] = a21;
    } else {
      float xnorm = fabsf(xx);
      float beta = -copysignf(slapy2f(alpha, xnorm), alpha);
      tau = (beta - alpha) / beta;
      float sc = 1.f / (alpha - beta);
      v2 = xx * sc;
      e[0] = beta;
      float x1 = tau * a11 + tau * (a21 * v2);
      float x2 = tau * a21 + (tau * v2) * a22;
      float dotxv = x1 + x2 * v2;
      float aw = (-0.5f * tau) * dotxv;
      float w1 = x1 + aw;
      float w2 = x2 + aw * v2;
      d[0] = a00;
      d[1] = (a11 - w1) - w1;
      e[1] = (a21 - v2 * w1) - w2;
      d[2] = (a22 - v2 * w2) - w2 * v2;
    }
  }
  Z[0][0] = 1.f; Z[0][1] = 0.f; Z[0][2] = 0.f;
  Z[1][0] = 0.f; Z[1][1] = 1.f; Z[1][2] = 0.f;
  Z[2][0] = 0.f; Z[2][1] = 0.f; Z[2][2] = 1.f;

  int nmaxit = 90, jtot = 0, l1 = 1;
  int l = 0, lsv = 0, lend = 0, lendsv = 0, m = 0, iscale = 0;
  float anorm = 0.f, p = 0.f, g = 0.f, r = 0.f, c = 0.f, s = 0.f, rt1 = 0.f, rt2 = 0.f;
  float cw[2], sw[2];
  cw[0] = cw[1] = sw[0] = sw[1] = 0.f;

L10:
  if (l1 > 3) goto L160;
  if (l1 > 1) e[l1 - 2] = 0.f;
  if (l1 <= 2) {
    for (m = l1; m <= 2; ++m) {
      float tst = fabsf(e[m - 1]);
      if (tst == 0.f) goto L30;
      if (tst <= (sqrtf(fabsf(d[m - 1])) * sqrtf(fabsf(d[m]))) * eps) { e[m - 1] = 0.f; goto L30; }
    }
  }
  m = 3;
L30:
  l = l1; lsv = l; lend = m; lendsv = lend; l1 = m + 1;
  if (lend == l) goto L10;
  anorm = fabsf(d[lend - 1]);
  for (int i = l; i < lend; ++i) {
    anorm = fmaxf(anorm, fabsf(d[i - 1]));
    anorm = fmaxf(anorm, fabsf(e[i - 1]));
  }
  iscale = 0;
  if (anorm == 0.f) goto L10;
  if (anorm > ssfmax) {
    iscale = 1;
    float mul = ssfmax / anorm;
    for (int i = l; i <= lend; ++i) d[i - 1] *= mul;
    for (int i = l; i < lend; ++i) e[i - 1] *= mul;
  } else if (anorm < ssfmin) {
    iscale = 2;
    float mul = ssfmin / anorm;
    for (int i = l; i <= lend; ++i) d[i - 1] *= mul;
    for (int i = l; i < lend; ++i) e[i - 1] *= mul;
  }
  if (fabsf(d[lend - 1]) < fabsf(d[l - 1])) { lend = lsv; l = lendsv; }
  if (lend > l) goto L40; else goto L90;

L40:
  if (l != lend) {
    for (m = l; m <= lend - 1; ++m) {
      float tst = e[m - 1] * e[m - 1];
      if (tst <= (eps2 * fabsf(d[m - 1])) * fabsf(d[m]) + safmin) goto L60;
    }
  }
  m = lend;
L60:
  if (m < lend) e[m - 1] = 0.f;
  p = d[l - 1];
  if (m == l) goto L80;
  if (m == l + 1) {
    slaev2f(d[l - 1], e[l - 1], d[l], &rt1, &rt2, &c, &s);
    for (int i = 0; i < 3; ++i) {
      float t0 = Z[i][l], t1 = Z[i][l - 1];
      Z[i][l]     = c * t0 - s * t1;
      Z[i][l - 1] = s * t0 + c * t1;
    }
    d[l - 1] = rt1; d[l] = rt2; e[l - 1] = 0.f;
    l += 2;
    if (l <= lend) goto L40;
    goto L140;
  }
  if (jtot == nmaxit) goto L140;
  ++jtot;
  g = (d[l] - p) / (2.f * e[l - 1]);
  r = slapy2f(g, 1.f);
  g = d[m - 1] - p + e[l - 1] / (g + copysignf(r, g));
  s = 1.f; c = 1.f; p = 0.f;
  for (int i = m - 1; i >= l; --i) {
    float f = s * e[i - 1];
    float bb = c * e[i - 1];
    slartgf(g, f, &c, &s, &r);
    if (i != m - 1) e[i] = r;
    g = d[i] - p;
    r = (d[i - 1] - g) * s + 2.f * c * bb;
    p = s * r;
    d[i] = g + p;
    g = c * r - bb;
    cw[i - 1] = c; sw[i - 1] = -s;
  }
  {
    int mm = m - l + 1;
    for (int j = mm - 1; j >= 1; --j) {
      float ct = cw[l + j - 2], st = sw[l + j - 2];
      int hi = (l - 1) + j;
      for (int i = 0; i < 3; ++i) {
        float t0 = Z[i][hi], t1 = Z[i][hi - 1];
        Z[i][hi]     = ct * t0 - st * t1;
        Z[i][hi - 1] = st * t0 + ct * t1;
      }
    }
  }
  d[l - 1] = d[l - 1] - p;
  e[l - 1] = g;
  goto L40;
L80:
  d[l - 1] = p;
  ++l;
  if (l <= lend) goto L40;
  goto L140;

L90:
  if (l != lend) {
    for (m = l; m >= lend + 1; --m) {
      float tst = e[m - 2] * e[m - 2];
      if (tst <= (eps2 * fabsf(d[m - 1])) * fabsf(d[m - 2]) + safmin) goto L110;
    }
  }
  m = lend;
L110:
  if (m > lend) e[m - 2] = 0.f;
  p = d[l - 1];
  if (m == l) goto L130;
  if (m == l - 1) {
    slaev2f(d[l - 2], e[l - 2], d[l - 1], &rt1, &rt2, &c, &s);
    for (int i = 0; i < 3; ++i) {
      float t0 = Z[i][l - 1], t1 = Z[i][l - 2];
      Z[i][l - 1] = c * t0 - s * t1;
      Z[i][l - 2] = s * t0 + c * t1;
    }
    d[l - 2] = rt1; d[l - 1] = rt2; e[l - 2] = 0.f;
    l -= 2;
    if (l >= lend) goto L90;
    goto L140;
  }
  if (jtot == nmaxit) goto L140;
  ++jtot;
  g = (d[l - 2] - p) / (2.f * e[l - 2]);
  r = slapy2f(g, 1.f);
  g = d[m - 1] - p + e[l - 2] / (g + copysignf(r, g));
  s = 1.f; c = 1.f; p = 0.f;
  for (int i = m; i <= l - 1; ++i) {
    float f = s * e[i - 1];
    float bb = c * e[i - 1];
    slartgf(g, f, &c, &s, &r);
    if (i != m) e[i - 2] = r;
    g = d[i - 1] - p;
    r = (d[i] - g) * s + 2.f * c * bb;
    p = s * r;
    d[i - 1] = g + p;
    g = c * r - bb;
    cw[i - 1] = c; sw[i - 1] = s;
  }
  {
    int mm = l - m + 1;
    for (int j = 1; j <= mm - 1; ++j) {
      float ct = cw[m + j - 2], st = sw[m + j - 2];
      int lo = (m - 1) + (j - 1);
      for (int i = 0; i < 3; ++i) {
        float t0 = Z[i][lo + 1], t1 = Z[i][lo];
        Z[i][lo + 1] = ct * t0 - st * t1;
        Z[i][lo]     = st * t0 + ct * t1;
      }
    }
  }
  d[l - 1] = d[l - 1] - p;
  e[l - 2] = g;
  goto L90;
L130:
  d[l - 1] = p;
  --l;
  if (l >= lend) goto L90;
  goto L140;

L140:
  if (iscale == 1) {
    float mul = anorm / ssfmax;
    for (int i = lsv; i <= lendsv; ++i) d[i - 1] *= mul;
    for (int i = lsv; i < lendsv; ++i) e[i - 1] *= mul;
  } else if (iscale == 2) {
    float mul = anorm / ssfmin;
    for (int i = lsv; i <= lendsv; ++i) d[i - 1] *= mul;
    for (int i = lsv; i < lendsv; ++i) e[i - 1] *= mul;
  }
  if (jtot < nmaxit) goto L10;
  goto L160;

L160:
  for (int ii = 2; ii <= 3; ++ii) {
    int i0 = ii - 1, k = i0;
    float pp = d[i0 - 1];
    for (int j = ii; j <= 3; ++j) {
      if (d[j - 1] < pp) { k = j; pp = d[j - 1]; }
    }
    if (k != i0) {
      d[k - 1] = d[i0 - 1]; d[i0 - 1] = pp;
      for (int rr2 = 0; rr2 < 3; ++rr2) {
        float t = Z[rr2][i0 - 1]; Z[rr2][i0 - 1] = Z[rr2][k - 1]; Z[rr2][k - 1] = t;
      }
    }
  }
  if (tau != 0.f) {
    for (int j = 0; j < 3; ++j) {
      float wj = Z[1][j] + v2 * Z[2][j];
      Z[1][j] = Z[1][j] - tau * wj;
      Z[2][j] = Z[2][j] - (tau * wj) * v2;
    }
  }
  vec[0] = Z[0][0]; vec[1] = Z[1][0]; vec[2] = Z[2][0];
  eval[0] = d[0]; eval[1] = d[1]; eval[2] = d[2];
}

// ------- branchless sorted top-20 insert, lexicographic (d2, j) key -------
__device__ __forceinline__ void insert20lex(float d2, int j, float bd[KNN], int bi[KNN]) {
  bool c[KNN];
#pragma unroll
  for (int k = 0; k < KNN; ++k)
    c[k] = (d2 < bd[k]) || (d2 == bd[k] && j < bi[k]);
#pragma unroll
  for (int k = KNN - 1; k >= 1; --k) {
    bd[k] = c[k - 1] ? bd[k - 1] : (c[k] ? d2 : bd[k]);
    bi[k] = c[k - 1] ? bi[k - 1] : (c[k] ? j : bi[k]);
  }
  bd[0] = c[0] ? d2 : bd[0];
  bi[0] = c[0] ? j : bi[0];
}

// ---------------- Kernels ----------------

__global__ void prep_kernel(const float* __restrict__ pc, float4* __restrict__ pts4, int total) {
  int i = blockIdx.x * blockDim.x + threadIdx.x;
  if (i < total) {
    float x = pc[i * 3 + 0], y = pc[i * 3 + 1], z = pc[i * 3 + 2];
    pts4[i] = make_float4(x, y, z, fmaf(z, z, fmaf(y, y, x * x)));
  }
}

// Scan kernel: 32 queries x 8 subs (256 thr). NO histogram / NO pass-1 LDS:
// pass1 keeps a branchless register top-3 per sub; thr = max of 8 sub-thirds.
// Pass2: pooled collect (CAPS=192). Wave0 lanes 0..31: lex register top-20.
// Exact fallback if raw<20 (degenerate ties) or raw>CAPS (tail overflow).
__global__ __launch_bounds__(256) void knn_scan_kernel(const float4* __restrict__ pts4,
                                                       float* __restrict__ knnd,
                                                       int* __restrict__ knni, int total) {
  __shared__ float sub3[SUBS][QPB];   // 1 KiB
  __shared__ float cbuf[CAPS][QPB];   // 24 KiB
  __shared__ int   ibuf[CAPS][QPB];   // 24 KiB
  __shared__ int   qcnt[QPB];

  const int t = threadIdx.x;
  const int q = t & (QPB - 1);
  const int s = t >> 5;                            // sub 0..7
  const int b = blockIdx.x >> 7;                   // 128 blocks of 32 queries per batch
  const int n = ((blockIdx.x & 127) << 5) + q;
  const int p = (b << 12) + n;
  const float4* __restrict__ P = pts4 + ((size_t)b << 12);
  const float4 me = P[n];
  const float xi = me.x, yi = me.y, zi = me.z, sqi = me.w;

  if (t < QPB) qcnt[t] = 0;

  const int j0 = s << 9;                           // 512 candidates per sub
  // ---- pass 1: branchless register top-3 of d2 (no LDS, no atomics) ----
  float t0 = __builtin_inff(), t1 = __builtin_inff(), t2 = __builtin_inff();
  for (int jj = 0; jj < 512; jj += 8) {
    float4 cc[8];
#pragma unroll
    for (int u = 0; u < 8; ++u) cc[u] = P[j0 + jj + u];
#pragma unroll
    for (int u = 0; u < 8; ++u) {
      float dot = fmaf(zi, cc[u].z, fmaf(yi, cc[u].y, xi * cc[u].x));
      float d2 = fmaf(-2.f, dot, sqi + cc[u].w);
      bool c0 = d2 < t0, c1 = d2 < t1, c2 = d2 < t2;
      t2 = c1 ? t1 : (c2 ? d2 : t2);
      t1 = c0 ? t0 : (c1 ? d2 : t1);
      t0 = c0 ? d2 : t0;
    }
  }
  sub3[s][q] = t2;
  __syncthreads();

  // thr = max over subs of (3rd smallest): each sub has >=2 strictly below,
  // non-max subs >=3 -> >=23 collected on distinct values.
  float thr = sub3[0][q];
#pragma unroll
  for (int k = 1; k < SUBS; ++k) thr = fmaxf(thr, sub3[k][q]);

  // ---- pass 2: pooled collect below threshold ----
  for (int jj = 0; jj < 512; jj += 8) {
    float4 cc[8];
#pragma unroll
    for (int u = 0; u < 8; ++u) cc[u] = P[j0 + jj + u];
#pragma unroll
    for (int u = 0; u < 8; ++u) {
      float dot = fmaf(zi, cc[u].z, fmaf(yi, cc[u].y, xi * cc[u].x));
      float d2 = fmaf(-2.f, dot, sqi + cc[u].w);
      if (d2 < thr) {
        int slot = atomicAdd(&qcnt[q], 1);
        if (slot < CAPS) {
          cbuf[slot][q] = d2;
          ibuf[slot][q] = j0 + jj + u;
        }
      }
    }
  }
  __syncthreads();

  if (s != 0) return;                              // lanes 0..31 of wave 0 finish

  float bd[KNN]; int bi[KNN];
#pragma unroll
  for (int k = 0; k < KNN; ++k) { bd[k] = __builtin_inff(); bi[k] = 0; }

  const int raw = qcnt[q];
  const int cnt = min(raw, CAPS);
  const bool bad = (raw > CAPS) || (raw < KNN);
  for (int i = 0; i < CAPS; ++i) {
    if (__all(i >= cnt)) break;
    if (i < cnt) {
      float d2 = cbuf[i][q]; int jj = ibuf[i][q];
      if (d2 < bd[KNN - 1] || (d2 == bd[KNN - 1] && jj < bi[KNN - 1]))
        insert20lex(d2, jj, bd, bi);
    }
  }
  // exact fallback (correctness guarantee; ~never taken on real data)
  if (__any(bad)) {
    if (bad) {
#pragma unroll
      for (int k = 0; k < KNN; ++k) { bd[k] = __builtin_inff(); bi[k] = 0; }
    }
    for (int j = 0; j < NPT; ++j) {
      float4 cj = P[j];
      float dot = fmaf(zi, cj.z, fmaf(yi, cj.y, xi * cj.x));
      float d2 = fmaf(-2.f, dot, sqi + cj.w);
      if (bad && (d2 < bd[KNN - 1] || (d2 == bd[KNN - 1] && j < bi[KNN - 1])))
        insert20lex(d2, j, bd, bi);
    }
  }

#pragma unroll
  for (int k = 0; k < KNN; ++k) {
    knnd[k * total + p] = bd[k];
    knni[k * total + p] = bi[k];
  }
}

// One thread per query: gather 20 neighbors, dist feats + covariance + eig.
__global__ __launch_bounds__(64) void feat_kernel(const float4* __restrict__ pts4,
                                                  const float* __restrict__ knnd,
                                                  const int* __restrict__ knni,
                                                  float* __restrict__ feat, int total) {
  const int p = blockIdx.x * 64 + threadIdx.x;
  const int b = p >> 12;
  const float4* __restrict__ P = pts4 + ((size_t)b << 12);
  const float4 me = P[p & 4095];
  const float xi = me.x, yi = me.y, zi = me.z;

  float bd[KNN]; int bi[KNN];
#pragma unroll
  for (int k = 0; k < KNN; ++k) {
    bd[k] = knnd[k * total + p];
    bi[k] = knni[k * total + p];
  }

  float sumd = 0.f, maxd = 0.f, mux = 0.f, muy = 0.f, muz = 0.f;
#pragma unroll
  for (int k = 0; k < KNN; ++k) {
    float dist = sqrtf(fmaxf(bd[k], 0.f) + 1e-12f);
    sumd += dist;
    maxd = fmaxf(maxd, dist);
    float4 nb = P[bi[k]];
    mux += nb.x; muy += nb.y; muz += nb.z;
  }
  float meand = sumd / 20.f;
  mux /= 20.f; muy /= 20.f; muz /= 20.f;

  float cxx = 0.f, cxy = 0.f, cxz = 0.f, cyy = 0.f, cyz = 0.f, czz = 0.f;
#pragma unroll
  for (int k = 0; k < KNN; ++k) {
    float4 nb = P[bi[k]];                          // L1-hot re-gather
    float dx = nb.x - mux, dy = nb.y - muy, dz = nb.z - muz;
    cxx = fmaf(dx, dx, cxx); cxy = fmaf(dx, dy, cxy); cxz = fmaf(dx, dz, cxz);
    cyy = fmaf(dy, dy, cyy); cyz = fmaf(dy, dz, cyz); czz = fmaf(dz, dz, czz);
  }
  cxx /= 20.f; cxy /= 20.f; cxz /= 20.f; cyy /= 20.f; cyz /= 20.f; czz /= 20.f;

  float vec[3], ev[3];
  eig3_lapack(cxx, cxy, cyy, cxz, cyz, czz, vec, ev);
  float curv = ev[0] / (((ev[0] + ev[1]) + ev[2]) + 1e-8f);

  feat[0 * total + p] = xi;
  feat[1 * total + p] = yi;
  feat[2 * total + p] = zi;
  feat[3 * total + p] = vec[0];
  feat[4 * total + p] = vec[1];
  feat[5 * total + p] = vec[2];
  feat[6 * total + p] = curv;
  feat[7 * total + p] = meand;
  feat[8 * total + p] = maxd;
}

// Block: 64 points x 4 waves. Wave w computes h1/h2 for its lane's point
// (redundant x4, weight addresses uniform -> s_loads; W3 row forced to SGPR
// via readfirstlane) and emits its 64 of the 256 output channels.
__global__ __launch_bounds__(256) void mlp_kernel(const float* __restrict__ feat,
    const float* __restrict__ W1, const float* __restrict__ B1,
    const float* __restrict__ W2, const float* __restrict__ B2,
    const float* __restrict__ W3, const float* __restrict__ B3,
    float* __restrict__ out, int total) {
  const int t = threadIdx.x;
  const int l = t & 63;
  const int w = t >> 6;                            // channel quarter 0..3
  const int p = blockIdx.x * 64 + l;

  float f[9];
#pragma unroll
  for (int c = 0; c < 9; ++c) f[c] = feat[c * total + p];

  float h1[64];
#pragma unroll
  for (int o = 0; o < 64; ++o) {
    float acc = B1[o];
#pragma unroll
    for (int i = 0; i < 9; ++i) acc = fmaf(f[i], W1[o * 9 + i], acc);
    h1[o] = fmaxf(acc, 0.f);
  }
  float h2[128];
#pragma unroll
  for (int o = 0; o < 128; ++o) {
    const float* wp = W2 + o * 64;
    float a0 = 0.f, a1 = 0.f, a2 = 0.f, a3 = 0.f;
#pragma unroll
    for (int i = 0; i < 64; i += 4) {
      a0 = fmaf(h1[i    ], wp[i    ], a0);
      a1 = fmaf(h1[i + 1], wp[i + 1], a1);
      a2 = fmaf(h1[i + 2], wp[i + 2], a2);
      a3 = fmaf(h1[i + 3], wp[i + 3], a3);
    }
    h2[o] = fmaxf(B2[o] + ((a0 + a1) + (a2 + a3)), 0.f);
  }

  const int b = p >> 12;
  const int n = p & 4095;
  float* op = out + (size_t)b * (256 * 4096) + n;
  const int obase = w << 6;
#pragma unroll 2
  for (int oo = 0; oo < 64; ++oo) {
    const int o = __builtin_amdgcn_readfirstlane(obase + oo);  // force SGPR row
    const float* wp = W3 + o * 128;
    float a0 = 0.f, a1 = 0.f, a2 = 0.f, a3 = 0.f;
#pragma unroll
    for (int i = 0; i < 128; i += 4) {
      a0 = fmaf(h2[i    ], wp[i    ], a0);
      a1 = fmaf(h2[i + 1], wp[i + 1], a1);
      a2 = fmaf(h2[i + 2], wp[i + 2], a2);
      a3 = fmaf(h2[i + 3], wp[i + 3], a3);
    }
    op[(size_t)o * 4096] = B3[o] + ((a0 + a1) + (a2 + a3));
  }
}

extern "C" void kernel_launch(void* const* d_in, const int* in_sizes, int n_in,
                              void* d_out, int out_size, void* d_ws, size_t ws_size,
                              hipStream_t stream) {
  const float* pc = (const float*)d_in[0];
  const float* W1 = (const float*)d_in[1];
  const float* b1 = (const float*)d_in[2];
  const float* W2 = (const float*)d_in[3];
  const float* b2 = (const float*)d_in[4];
  const float* W3 = (const float*)d_in[5];
  const float* b3 = (const float*)d_in[6];
  // d_in[7] = vis_mask (all ones) -- unused, matches reference semantics

  const int total = in_sizes[0] / 3;               // B*N = 32768
  float4* pts4 = (float4*)d_ws;
  float* feat = (float*)((char*)d_ws + (size_t)total * sizeof(float4));
  float* outp = (float*)d_out;
  // Stage top-20 lists in d_out (5.2 MB of 32 MB), overwritten by MLP later.
  float* knnd = outp;
  int*   knni = (int*)(outp + (size_t)KNN * total);

  prep_kernel<<<(total + 255) / 256, 256, 0, stream>>>(pc, pts4, total);
  knn_scan_kernel<<<total / QPB, 256, 0, stream>>>(pts4, knnd, knni, total);
  feat_kernel<<<total / 64, 64, 0, stream>>>(pts4, knnd, knni, feat, total);
  mlp_kernel<<<total / 64, 256, 0, stream>>>(feat, W1, b1, W2, b2, W3, b3, outp, total);
}

// Round 8
// 663.148 us; speedup vs baseline: 2.9516x; 1.0131x over previous
//
#include <hip/hip_runtime.h>
#include <math.h>

// ============================================================================
// GeometricModule: KNN(20) -> PCA normal/curvature (LAPACK-replica eigh) ->
// local dist feats -> per-point MLP 9->64->128->256, out (B,256,N) f32.
//
// R8: (a) scan LDS diet: no cbuf (merge recomputes d2 from idx, bit-identical),
//     ibuf as ushort -> LDS 13.3KB -> 16 waves/CU (VGPR-bound).
//     (b) feat: eig scratch arrays (Z/d/e/cw/sw) moved to thread-strided LDS
//     (identical arithmetic/control flow; kills exposed scratch latency).
//     Selection semantics == jax top_k (lex (d2,j) insert). Eig arithmetic
//     byte-identical to R1-R7 (all passed).
// ============================================================================

#define LARTG_NEW 1
#define NPT 4096
#define KNN 20
#define CAPS 192  // pooled per-query collect capacity (E~52, P(>192)~0)
#define QPB 32    // queries per scan block
#define SUBS 8

// ---------------- LAPACK f32 helper replicas ----------------

__device__ __forceinline__ float slapy2f(float x, float y) {
#pragma clang fp contract(off)
  float xa = fabsf(x), ya = fabsf(y);
  float w = fmaxf(xa, ya);
  float z = fminf(xa, ya);
  if (z == 0.f) return w;
  float q = z / w;
  return w * sqrtf(1.f + q * q);
}

__device__ __forceinline__ void slartgf(float f, float g, float* cs, float* sn, float* rr) {
#pragma clang fp contract(off)
#if LARTG_NEW
  const float safmin = 1.17549435e-38f;
  const float safmax = 8.5070592e37f;
  const float rtmin  = 1.0842022e-19f;
  const float rtmax  = 6.5221643e18f;
  float f1 = fabsf(f), g1 = fabsf(g);
  if (g == 0.f) { *cs = 1.f; *sn = 0.f; *rr = f; }
  else if (f == 0.f) { *cs = 0.f; *sn = copysignf(1.f, g); *rr = g1; }
  else {
    if (f1 > rtmin && f1 < rtmax && g1 > rtmin && g1 < rtmax) {
      float dd = sqrtf(f * f + g * g);
      *cs = f1 / dd;
      float r = copysignf(dd, f);
      *sn = g / r;
      *rr = r;
    } else {
      float u = fminf(safmax, fmaxf(safmin, fmaxf(f1, g1)));
      float fs = f / u, gs = g / u;
      float dd = sqrtf(fs * fs + gs * gs);
      *cs = fabsf(fs) / dd;
      float r = copysignf(dd, f);
      *sn = gs / r;
      *rr = r * u;
    }
  }
#else
  if (g == 0.f) { *cs = 1.f; *sn = 0.f; *rr = f; }
  else if (f == 0.f) { *cs = 0.f; *sn = 1.f; *rr = g; }
  else {
    float r = sqrtf(f * f + g * g);
    float c = f / r, s = g / r;
    if (fabsf(f) > fabsf(g) && c < 0.f) { c = -c; s = -s; r = -r; }
    *cs = c; *sn = s; *rr = r;
  }
#endif
}

__device__ __forceinline__ void slaev2f(float a, float b, float c,
                                        float* rt1, float* rt2, float* cs1, float* sn1) {
#pragma clang fp contract(off)
  float sm = a + c, df = a - c, adf = fabsf(df);
  float tb = b + b, ab = fabsf(tb);
  float acmx, acmn;
  if (fabsf(a) > fabsf(c)) { acmx = a; acmn = c; } else { acmx = c; acmn = a; }
  float rt;
  if (adf > ab)      { float t = ab / adf; rt = adf * sqrtf(1.f + t * t); }
  else if (adf < ab) { float t = adf / ab; rt = ab * sqrtf(1.f + t * t); }
  else               { rt = ab * sqrtf(2.f); }
  int sgn1;
  if (sm < 0.f)      { *rt1 = 0.5f * (sm - rt); sgn1 = -1; *rt2 = (acmx / *rt1) * acmn - (b / *rt1) * b; }
  else if (sm > 0.f) { *rt1 = 0.5f * (sm + rt); sgn1 = 1;  *rt2 = (acmx / *rt1) * acmn - (b / *rt1) * b; }
  else               { *rt1 = 0.5f * rt; *rt2 = -0.5f * rt; sgn1 = 1; }
  float cs; int sgn2;
  if (df >= 0.f) { cs = df + rt; sgn2 = 1; } else { cs = df - rt; sgn2 = -1; }
  float acs = fabsf(cs);
  if (acs > ab) {
    float ct = -tb / cs;
    *sn1 = 1.f / sqrtf(1.f + ct * ct);
    *cs1 = ct * *sn1;
  } else {
    if (ab == 0.f) { *cs1 = 1.f; *sn1 = 0.f; }
    else {
      float tn = -cs / tb;
      *cs1 = 1.f / sqrtf(1.f + tn * tn);
      *sn1 = tn * *cs1;
    }
  }
  if (sgn1 == sgn2) { float tn = *cs1; *cs1 = -*sn1; *sn1 = tn; }
}

// ssyevd path for 3x3 (lower): ssytd2 -> ssteqr('I') -> sormtr.
// Storage for Z/d/e/cw/sw lives in LDS via thread-strided macros (FS=stride).
// Arithmetic and control flow identical to the register/scratch version
// that passed R1-R7; only the storage location changed.
#define FS 64
#define Zm(i_, j_) ldsZ[(((i_) * 3 + (j_)) ) * FS]
#define dm(i_)     ldsD[(i_) * FS]
#define em(i_)     ldsE[(i_) * FS]
#define cwm(i_)    ldsCW[(i_) * FS]
#define swm(i_)    ldsSW[(i_) * FS]

__device__ void eig3_lapack_lds(float a00, float a10, float a11, float a20, float a21, float a22,
                                float* __restrict__ ldsZ, float* __restrict__ ldsD,
                                float* __restrict__ ldsE, float* __restrict__ ldsCW,
                                float* __restrict__ ldsSW,
                                float vec[3], float eval[3]) {
#pragma clang fp contract(off)
  const float eps    = 5.9604645e-08f;
  const float eps2   = 3.5527137e-15f;
  const float safmin = 1.17549435e-38f;
  const float ssfmax = 3.0744573e18f;
  const float ssfmin = 3.0517578e-05f;

  float tau, v2;

  // ---- ssytd2 'L' ----
  {
    float alpha = a10, xx = a20;
    if (xx == 0.f) {
      tau = 0.f; v2 = 0.f;
      em(0) = alpha;
      dm(0) = a00; dm(1) = a11; dm(2) = a22; em(1) = a21;
    } else {
      float xnorm = fabsf(xx);
      float beta = -copysignf(slapy2f(alpha, xnorm), alpha);
      tau = (beta - alpha) / beta;
      float sc = 1.f / (alpha - beta);
      v2 = xx * sc;
      em(0) = beta;
      float x1 = tau * a11 + tau * (a21 * v2);
      float x2 = tau * a21 + (tau * v2) * a22;
      float dotxv = x1 + x2 * v2;
      float aw = (-0.5f * tau) * dotxv;
      float w1 = x1 + aw;
      float w2 = x2 + aw * v2;
      dm(0) = a00;
      dm(1) = (a11 - w1) - w1;
      em(1) = (a21 - v2 * w1) - w2;
      dm(2) = (a22 - v2 * w2) - w2 * v2;
    }
  }
  Zm(0,0) = 1.f; Zm(0,1) = 0.f; Zm(0,2) = 0.f;
  Zm(1,0) = 0.f; Zm(1,1) = 1.f; Zm(1,2) = 0.f;
  Zm(2,0) = 0.f; Zm(2,1) = 0.f; Zm(2,2) = 1.f;

  int nmaxit = 90, jtot = 0, l1 = 1;
  int l = 0, lsv = 0, lend = 0, lendsv = 0, m = 0, iscale = 0;
  float anorm = 0.f, p = 0.f, g = 0.f, r = 0.f, c = 0.f, s = 0.f, rt1 = 0.f, rt2 = 0.f;
  cwm(0) = 0.f; cwm(1) = 0.f; swm(0) = 0.f; swm(1) = 0.f;

L10:
  if (l1 > 3) goto L160;
  if (l1 > 1) em(l1 - 2) = 0.f;
  if (l1 <= 2) {
    for (m = l1; m <= 2; ++m) {
      float tst = fabsf(em(m - 1));
      if (tst == 0.f) goto L30;
      if (tst <= (sqrtf(fabsf(dm(m - 1))) * sqrtf(fabsf(dm(m)))) * eps) { em(m - 1) = 0.f; goto L30; }
    }
  }
  m = 3;
L30:
  l = l1; lsv = l; lend = m; lendsv = lend; l1 = m + 1;
  if (lend == l) goto L10;
  anorm = fabsf(dm(lend - 1));
  for (int i = l; i < lend; ++i) {
    anorm = fmaxf(anorm, fabsf(dm(i - 1)));
    anorm = fmaxf(anorm, fabsf(em(i - 1)));
  }
  iscale = 0;
  if (anorm == 0.f) goto L10;
  if (anorm > ssfmax) {
    iscale = 1;
    float mul = ssfmax / anorm;
    for (int i = l; i <= lend; ++i) dm(i - 1) = dm(i - 1) * mul;
    for (int i = l; i < lend; ++i) em(i - 1) = em(i - 1) * mul;
  } else if (anorm < ssfmin) {
    iscale = 2;
    float mul = ssfmin / anorm;
    for (int i = l; i <= lend; ++i) dm(i - 1) = dm(i - 1) * mul;
    for (int i = l; i < lend; ++i) em(i - 1) = em(i - 1) * mul;
  }
  if (fabsf(dm(lend - 1)) < fabsf(dm(l - 1))) { lend = lsv; l = lendsv; }
  if (lend > l) goto L40; else goto L90;

  // ================= QL =================
L40:
  if (l != lend) {
    for (m = l; m <= lend - 1; ++m) {
      float tst = em(m - 1) * em(m - 1);
      if (tst <= (eps2 * fabsf(dm(m - 1))) * fabsf(dm(m)) + safmin) goto L60;
    }
  }
  m = lend;
L60:
  if (m < lend) em(m - 1) = 0.f;
  p = dm(l - 1);
  if (m == l) goto L80;
  if (m == l + 1) {
    slaev2f(dm(l - 1), em(l - 1), dm(l), &rt1, &rt2, &c, &s);
    for (int i = 0; i < 3; ++i) {
      float t0 = Zm(i, l), t1 = Zm(i, l - 1);
      Zm(i, l)     = c * t0 - s * t1;
      Zm(i, l - 1) = s * t0 + c * t1;
    }
    dm(l - 1) = rt1; dm(l) = rt2; em(l - 1) = 0.f;
    l += 2;
    if (l <= lend) goto L40;
    goto L140;
  }
  if (jtot == nmaxit) goto L140;
  ++jtot;
  g = (dm(l) - p) / (2.f * em(l - 1));
  r = slapy2f(g, 1.f);
  g = dm(m - 1) - p + em(l - 1) / (g + copysignf(r, g));
  s = 1.f; c = 1.f; p = 0.f;
  for (int i = m - 1; i >= l; --i) {
    float f = s * em(i - 1);
    float bb = c * em(i - 1);
    slartgf(g, f, &c, &s, &r);
    if (i != m - 1) em(i) = r;
    g = dm(i) - p;
    r = (dm(i - 1) - g) * s + 2.f * c * bb;
    p = s * r;
    dm(i) = g + p;
    g = c * r - bb;
    cwm(i - 1) = c; swm(i - 1) = -s;
  }
  {
    int mm = m - l + 1;
    for (int j = mm - 1; j >= 1; --j) {      // SLASR 'R','V','B'
      float ct = cwm(l + j - 2), st = swm(l + j - 2);
      int hi = (l - 1) + j;
      for (int i = 0; i < 3; ++i) {
        float t0 = Zm(i, hi), t1 = Zm(i, hi - 1);
        Zm(i, hi)     = ct * t0 - st * t1;
        Zm(i, hi - 1) = st * t0 + ct * t1;
      }
    }
  }
  dm(l - 1) = dm(l - 1) - p;
  em(l - 1) = g;
  goto L40;
L80:
  dm(l - 1) = p;
  ++l;
  if (l <= lend) goto L40;
  goto L140;

  // ================= QR =================
L90:
  if (l != lend) {
    for (m = l; m >= lend + 1; --m) {
      float tst = em(m - 2) * em(m - 2);
      if (tst <= (eps2 * fabsf(dm(m - 1))) * fabsf(dm(m - 2)) + safmin) goto L110;
    }
  }
  m = lend;
L110:
  if (m > lend) em(m - 2) = 0.f;
  p = dm(l - 1);
  if (m == l) goto L130;
  if (m == l - 1) {
    slaev2f(dm(l - 2), em(l - 2), dm(l - 1), &rt1, &rt2, &c, &s);
    for (int i = 0; i < 3; ++i) {            // SLASR 'R','V','F' single rot
      float t0 = Zm(i, l - 1), t1 = Zm(i, l - 2);
      Zm(i, l - 1) = c * t0 - s * t1;
      Zm(i, l - 2) = s * t0 + c * t1;
    }
    dm(l - 2) = rt1; dm(l - 1) = rt2; em(l - 2) = 0.f;
    l -= 2;
    if (l >= lend) goto L90;
    goto L140;
  }
  if (jtot == nmaxit) goto L140;
  ++jtot;
  g = (dm(l - 2) - p) / (2.f * em(l - 2));
  r = slapy2f(g, 1.f);
  g = dm(m - 1) - p + em(l - 2) / (g + copysignf(r, g));
  s = 1.f; c = 1.f; p = 0.f;
  for (int i = m; i <= l - 1; ++i) {
    float f = s * em(i - 1);
    float bb = c * em(i - 1);
    slartgf(g, f, &c, &s, &r);
    if (i != m) em(i - 2) = r;
    g = dm(i - 1) - p;
    r = (dm(i) - g) * s + 2.f * c * bb;
    p = s * r;
    dm(i - 1) = g + p;
    g = c * r - bb;
    cwm(i - 1) = c; swm(i - 1) = s;
  }
  {
    int mm = l - m + 1;
    for (int j = 1; j <= mm - 1; ++j) {      // SLASR 'R','V','F'
      float ct = cwm(m + j - 2), st = swm(m + j - 2);
      int lo = (m - 1) + (j - 1);
      for (int i = 0; i < 3; ++i) {
        float t0 = Zm(i, lo + 1), t1 = Zm(i, lo);
        Zm(i, lo + 1) = ct * t0 - st * t1;
        Zm(i, lo)     = st * t0 + ct * t1;
      }
    }
  }
  dm(l - 1) = dm(l - 1) - p;
  em(l - 2) = g;
  goto L90;
L130:
  dm(l - 1) = p;
  --l;
  if (l >= lend) goto L90;
  goto L140;

L140:
  if (iscale == 1) {
    float mul = anorm / ssfmax;
    for (int i = lsv; i <= lendsv; ++i) dm(i - 1) = dm(i - 1) * mul;
    for (int i = lsv; i < lendsv; ++i) em(i - 1) = em(i - 1) * mul;
  } else if (iscale == 2) {
    float mul = anorm / ssfmin;
    for (int i = lsv; i <= lendsv; ++i) dm(i - 1) = dm(i - 1) * mul;
    for (int i = lsv; i < lendsv; ++i) em(i - 1) = em(i - 1) * mul;
  }
  if (jtot < nmaxit) goto L10;
  goto L160;

L160:
  // selection sort ascending + column swaps (LAPACK ordering)
  for (int ii = 2; ii <= 3; ++ii) {
    int i0 = ii - 1, k = i0;
    float pp = dm(i0 - 1);
    for (int j = ii; j <= 3; ++j) {
      if (dm(j - 1) < pp) { k = j; pp = dm(j - 1); }
    }
    if (k != i0) {
      dm(k - 1) = dm(i0 - 1); dm(i0 - 1) = pp;
      for (int rr2 = 0; rr2 < 3; ++rr2) {
        float t = Zm(rr2, i0 - 1); Zm(rr2, i0 - 1) = Zm(rr2, k - 1); Zm(rr2, k - 1) = t;
      }
    }
  }
  // ---- sormtr: Z := H1 * Z (rows 1,2) ----
  if (tau != 0.f) {
    for (int j = 0; j < 3; ++j) {
      float wj = Zm(1, j) + v2 * Zm(2, j);
      Zm(1, j) = Zm(1, j) - tau * wj;
      Zm(2, j) = Zm(2, j) - (tau * wj) * v2;
    }
  }
  vec[0] = Zm(0, 0); vec[1] = Zm(1, 0); vec[2] = Zm(2, 0);
  eval[0] = dm(0); eval[1] = dm(1); eval[2] = dm(2);
}

// ------- branchless sorted top-20 insert, lexicographic (d2, j) key -------
__device__ __forceinline__ void insert20lex(float d2, int j, float bd[KNN], int bi[KNN]) {
  bool c[KNN];
#pragma unroll
  for (int k = 0; k < KNN; ++k)
    c[k] = (d2 < bd[k]) || (d2 == bd[k] && j < bi[k]);
#pragma unroll
  for (int k = KNN - 1; k >= 1; --k) {
    bd[k] = c[k - 1] ? bd[k - 1] : (c[k] ? d2 : bd[k]);
    bi[k] = c[k - 1] ? bi[k - 1] : (c[k] ? j : bi[k]);
  }
  bd[0] = c[0] ? d2 : bd[0];
  bi[0] = c[0] ? j : bi[0];
}

// ---------------- Kernels ----------------

__global__ void prep_kernel(const float* __restrict__ pc, float4* __restrict__ pts4, int total) {
  int i = blockIdx.x * blockDim.x + threadIdx.x;
  if (i < total) {
    float x = pc[i * 3 + 0], y = pc[i * 3 + 1], z = pc[i * 3 + 2];
    pts4[i] = make_float4(x, y, z, fmaf(z, z, fmaf(y, y, x * x)));
  }
}

// Scan kernel: 32 queries x 8 subs (256 thr). Pass1: register top-3 per sub;
// thr = max of 8 sub-thirds (>=23 below on distinct values). Pass2: pooled
// collect of INDICES ONLY (ushort). Merge recomputes d2 from idx (identical
// bits). Exact fallback if raw<20 or raw>CAPS.
__global__ __launch_bounds__(256) void knn_scan_kernel(const float4* __restrict__ pts4,
                                                       float* __restrict__ knnd,
                                                       int* __restrict__ knni, int total) {
  __shared__ float  sub3[SUBS][QPB];           // 1 KiB
  __shared__ unsigned short ibuf[CAPS][QPB];   // 12 KiB
  __shared__ int    qcnt[QPB];

  const int t = threadIdx.x;
  const int q = t & (QPB - 1);
  const int s = t >> 5;                            // sub 0..7
  const int b = blockIdx.x >> 7;                   // 128 blocks of 32 queries per batch
  const int n = ((blockIdx.x & 127) << 5) + q;
  const int p = (b << 12) + n;
  const float4* __restrict__ P = pts4 + ((size_t)b << 12);
  const float4 me = P[n];
  const float xi = me.x, yi = me.y, zi = me.z, sqi = me.w;

  if (t < QPB) qcnt[t] = 0;

  const int j0 = s << 9;                           // 512 candidates per sub
  // ---- pass 1: branchless register top-3 of d2 (no LDS, no atomics) ----
  float t0 = __builtin_inff(), t1 = __builtin_inff(), t2 = __builtin_inff();
  for (int jj = 0; jj < 512; jj += 8) {
    float4 cc[8];
#pragma unroll
    for (int u = 0; u < 8; ++u) cc[u] = P[j0 + jj + u];
#pragma unroll
    for (int u = 0; u < 8; ++u) {
      float dot = fmaf(zi, cc[u].z, fmaf(yi, cc[u].y, xi * cc[u].x));
      float d2 = fmaf(-2.f, dot, sqi + cc[u].w);
      bool c0 = d2 < t0, c1 = d2 < t1, c2 = d2 < t2;
      t2 = c1 ? t1 : (c2 ? d2 : t2);
      t1 = c0 ? t0 : (c1 ? d2 : t1);
      t0 = c0 ? d2 : t0;
    }
  }
  sub3[s][q] = t2;
  __syncthreads();

  float thr = sub3[0][q];
#pragma unroll
  for (int k = 1; k < SUBS; ++k) thr = fmaxf(thr, sub3[k][q]);

  // ---- pass 2: pooled collect of indices below threshold ----
  for (int jj = 0; jj < 512; jj += 8) {
    float4 cc[8];
#pragma unroll
    for (int u = 0; u < 8; ++u) cc[u] = P[j0 + jj + u];
#pragma unroll
    for (int u = 0; u < 8; ++u) {
      float dot = fmaf(zi, cc[u].z, fmaf(yi, cc[u].y, xi * cc[u].x));
      float d2 = fmaf(-2.f, dot, sqi + cc[u].w);
      if (d2 < thr) {
        int slot = atomicAdd(&qcnt[q], 1);
        if (slot < CAPS) ibuf[slot][q] = (unsigned short)(j0 + jj + u);
      }
    }
  }
  __syncthreads();

  if (s != 0) return;                              // lanes 0..31 of wave 0 finish

  float bd[KNN]; int bi[KNN];
#pragma unroll
  for (int k = 0; k < KNN; ++k) { bd[k] = __builtin_inff(); bi[k] = 0; }

  const int raw = qcnt[q];
  const int cnt = min(raw, CAPS);
  const bool bad = (raw > CAPS) || (raw < KNN);
  for (int i = 0; i < CAPS; ++i) {
    if (__all(i >= cnt)) break;
    if (i < cnt) {
      int jj = ibuf[i][q];
      float4 cj = P[jj];                           // L1-hot re-read
      float dot = fmaf(zi, cj.z, fmaf(yi, cj.y, xi * cj.x));
      float d2 = fmaf(-2.f, dot, sqi + cj.w);      // identical bits to pass2
      if (d2 < bd[KNN - 1] || (d2 == bd[KNN - 1] && jj < bi[KNN - 1]))
        insert20lex(d2, jj, bd, bi);
    }
  }
  // exact fallback (correctness guarantee; ~never taken on real data)
  if (__any(bad)) {
    if (bad) {
#pragma unroll
      for (int k = 0; k < KNN; ++k) { bd[k] = __builtin_inff(); bi[k] = 0; }
    }
    for (int j = 0; j < NPT; ++j) {
      float4 cj = P[j];
      float dot = fmaf(zi, cj.z, fmaf(yi, cj.y, xi * cj.x));
      float d2 = fmaf(-2.f, dot, sqi + cj.w);
      if (bad && (d2 < bd[KNN - 1] || (d2 == bd[KNN - 1] && j < bi[KNN - 1])))
        insert20lex(d2, j, bd, bi);
    }
  }

#pragma unroll
  for (int k = 0; k < KNN; ++k) {
    knnd[k * total + p] = bd[k];
    knni[k * total + p] = bi[k];
  }
}

// One thread per query: gather 20 neighbors, dist feats + covariance + eig.
// Eig working arrays live in thread-strided LDS (no scratch memory).
__global__ __launch_bounds__(64) void feat_kernel(const float4* __restrict__ pts4,
                                                  const float* __restrict__ knnd,
                                                  const int* __restrict__ knni,
                                                  float* __restrict__ feat, int total) {
  __shared__ float eZ[9 * FS];
  __shared__ float eD[3 * FS];
  __shared__ float eE[2 * FS];
  __shared__ float eCW[2 * FS];
  __shared__ float eSW[2 * FS];

  const int tid = threadIdx.x;
  const int p = blockIdx.x * 64 + tid;
  const int b = p >> 12;
  const float4* __restrict__ P = pts4 + ((size_t)b << 12);
  const float4 me = P[p & 4095];
  const float xi = me.x, yi = me.y, zi = me.z;

  float bd[KNN]; int bi[KNN];
#pragma unroll
  for (int k = 0; k < KNN; ++k) {
    bd[k] = knnd[k * total + p];
    bi[k] = knni[k * total + p];
  }

  float sumd = 0.f, maxd = 0.f, mux = 0.f, muy = 0.f, muz = 0.f;
#pragma unroll
  for (int k = 0; k < KNN; ++k) {
    float dist = sqrtf(fmaxf(bd[k], 0.f) + 1e-12f);
    sumd += dist;
    maxd = fmaxf(maxd, dist);
    float4 nb = P[bi[k]];
    mux += nb.x; muy += nb.y; muz += nb.z;
  }
  float meand = sumd / 20.f;
  mux /= 20.f; muy /= 20.f; muz /= 20.f;

  float cxx = 0.f, cxy = 0.f, cxz = 0.f, cyy = 0.f, cyz = 0.f, czz = 0.f;
#pragma unroll
  for (int k = 0; k < KNN; ++k) {
    float4 nb = P[bi[k]];                          // L1-hot re-gather
    float dx = nb.x - mux, dy = nb.y - muy, dz = nb.z - muz;
    cxx = fmaf(dx, dx, cxx); cxy = fmaf(dx, dy, cxy); cxz = fmaf(dx, dz, cxz);
    cyy = fmaf(dy, dy, cyy); cyz = fmaf(dy, dz, cyz); czz = fmaf(dz, dz, czz);
  }
  cxx /= 20.f; cxy /= 20.f; cxz /= 20.f; cyy /= 20.f; cyz /= 20.f; czz /= 20.f;

  float vec[3], ev[3];
  eig3_lapack_lds(cxx, cxy, cyy, cxz, cyz, czz,
                  &eZ[tid], &eD[tid], &eE[tid], &eCW[tid], &eSW[tid], vec, ev);
  float curv = ev[0] / (((ev[0] + ev[1]) + ev[2]) + 1e-8f);

  feat[0 * total + p] = xi;
  feat[1 * total + p] = yi;
  feat[2 * total + p] = zi;
  feat[3 * total + p] = vec[0];
  feat[4 * total + p] = vec[1];
  feat[5 * total + p] = vec[2];
  feat[6 * total + p] = curv;
  feat[7 * total + p] = meand;
  feat[8 * total + p] = maxd;
}

// Block: 64 points x 4 waves. Wave w computes h1/h2 for its lane's point
// (redundant x4, weight addresses uniform -> s_loads; W3 row forced to SGPR
// via readfirstlane) and emits its 64 of the 256 output channels.
__global__ __launch_bounds__(256) void mlp_kernel(const float* __restrict__ feat,
    const float* __restrict__ W1, const float* __restrict__ B1,
    const float* __restrict__ W2, const float* __restrict__ B2,
    const float* __restrict__ W3, const float* __restrict__ B3,
    float* __restrict__ out, int total) {
  const int t = threadIdx.x;
  const int l = t & 63;
  const int w = t >> 6;                            // channel quarter 0..3
  const int p = blockIdx.x * 64 + l;

  float f[9];
#pragma unroll
  for (int c = 0; c < 9; ++c) f[c] = feat[c * total + p];

  float h1[64];
#pragma unroll
  for (int o = 0; o < 64; ++o) {
    float acc = B1[o];
#pragma unroll
    for (int i = 0; i < 9; ++i) acc = fmaf(f[i], W1[o * 9 + i], acc);
    h1[o] = fmaxf(acc, 0.f);
  }
  float h2[128];
#pragma unroll
  for (int o = 0; o < 128; ++o) {
    const float* wp = W2 + o * 64;
    float a0 = 0.f, a1 = 0.f, a2 = 0.f, a3 = 0.f;
#pragma unroll
    for (int i = 0; i < 64; i += 4) {
      a0 = fmaf(h1[i    ], wp[i    ], a0);
      a1 = fmaf(h1[i + 1], wp[i + 1], a1);
      a2 = fmaf(h1[i + 2], wp[i + 2], a2);
      a3 = fmaf(h1[i + 3], wp[i + 3], a3);
    }
    h2[o] = fmaxf(B2[o] + ((a0 + a1) + (a2 + a3)), 0.f);
  }

  const int b = p >> 12;
  const int n = p & 4095;
  float* op = out + (size_t)b * (256 * 4096) + n;
  const int obase = w << 6;
#pragma unroll 2
  for (int oo = 0; oo < 64; ++oo) {
    const int o = __builtin_amdgcn_readfirstlane(obase + oo);  // force SGPR row
    const float* wp = W3 + o * 128;
    float a0 = 0.f, a1 = 0.f, a2 = 0.f, a3 = 0.f;
#pragma unroll
    for (int i = 0; i < 128; i += 4) {
      a0 = fmaf(h2[i    ], wp[i    ], a0);
      a1 = fmaf(h2[i + 1], wp[i + 1], a1);
      a2 = fmaf(h2[i + 2], wp[i + 2], a2);
      a3 = fmaf(h2[i + 3], wp[i + 3], a3);
    }
    op[(size_t)o * 4096] = B3[o] + ((a0 + a1) + (a2 + a3));
  }
}

extern "C" void kernel_launch(void* const* d_in, const int* in_sizes, int n_in,
                              void* d_out, int out_size, void* d_ws, size_t ws_size,
                              hipStream_t stream) {
  const float* pc = (const float*)d_in[0];
  const float* W1 = (const float*)d_in[1];
  const float* b1 = (const float*)d_in[2];
  const float* W2 = (const float*)d_in[3];
  const float* b2 = (const float*)d_in[4];
  const float* W3 = (const float*)d_in[5];
  const float* b3 = (const float*)d_in[6];
  // d_in[7] = vis_mask (all ones) -- unused, matches reference semantics

  const int total = in_sizes[0] / 3;               // B*N = 32768
  float4* pts4 = (float4*)d_ws;
  float* feat = (float*)((char*)d_ws + (size_t)total * sizeof(float4));
  float* outp = (float*)d_out;
  // Stage top-20 lists in d_out (5.2 MB of 32 MB), overwritten by MLP later.
  float* knnd = outp;
  int*   knni = (int*)(outp + (size_t)KNN * total);

  prep_kernel<<<(total + 255) / 256, 256, 0, stream>>>(pc, pts4, total);
  knn_scan_kernel<<<total / QPB, 256, 0, stream>>>(pts4, knnd, knni, total);
  feat_kernel<<<total / 64, 64, 0, stream>>>(pts4, knnd, knni, feat, total);
  mlp_kernel<<<total / 64, 256, 0, stream>>>(feat, W1, b1, W2, b2, W3, b3, outp, total);
}

// Round 9
// 384.186 us; speedup vs baseline: 5.0949x; 1.7261x over previous
//
#include <hip/hip_runtime.h>
#include <math.h>

// ============================================================================
// GeometricModule: KNN(20) -> PCA normal/curvature (LAPACK-replica eigh) ->
// local dist feats -> per-point MLP 9->64->128->256, out (B,256,N) f32.
//
// R9: GEMM-style MLP. R8's mlp serialized on wave-uniform s_load weight
//     chains (47cyc/FMA, VALUBusy 11%). Now lanes = output channels with
//     pre-transposed weights (coalesced 16B/lane vector loads), activations
//     broadcast from LDS, register accumulator tiles, contiguous stores.
//     scan/feat/prep identical to R8 (passed). Eig path byte-identical R1-R8.
// ============================================================================

#define LARTG_NEW 1
#define NPT 4096
#define KNN 20
#define CAPS 192  // pooled per-query collect capacity (E~52, P(>192)~0)
#define QPB 32    // queries per scan block
#define SUBS 8

// ---------------- LAPACK f32 helper replicas ----------------

__device__ __forceinline__ float slapy2f(float x, float y) {
#pragma clang fp contract(off)
  float xa = fabsf(x), ya = fabsf(y);
  float w = fmaxf(xa, ya);
  float z = fminf(xa, ya);
  if (z == 0.f) return w;
  float q = z / w;
  return w * sqrtf(1.f + q * q);
}

__device__ __forceinline__ void slartgf(float f, float g, float* cs, float* sn, float* rr) {
#pragma clang fp contract(off)
#if LARTG_NEW
  const float safmin = 1.17549435e-38f;
  const float safmax = 8.5070592e37f;
  const float rtmin  = 1.0842022e-19f;
  const float rtmax  = 6.5221643e18f;
  float f1 = fabsf(f), g1 = fabsf(g);
  if (g == 0.f) { *cs = 1.f; *sn = 0.f; *rr = f; }
  else if (f == 0.f) { *cs = 0.f; *sn = copysignf(1.f, g); *rr = g1; }
  else {
    if (f1 > rtmin && f1 < rtmax && g1 > rtmin && g1 < rtmax) {
      float dd = sqrtf(f * f + g * g);
      *cs = f1 / dd;
      float r = copysignf(dd, f);
      *sn = g / r;
      *rr = r;
    } else {
      float u = fminf(safmax, fmaxf(safmin, fmaxf(f1, g1)));
      float fs = f / u, gs = g / u;
      float dd = sqrtf(fs * fs + gs * gs);
      *cs = fabsf(fs) / dd;
      float r = copysignf(dd, f);
      *sn = gs / r;
      *rr = r * u;
    }
  }
#else
  if (g == 0.f) { *cs = 1.f; *sn = 0.f; *rr = f; }
  else if (f == 0.f) { *cs = 0.f; *sn = 1.f; *rr = g; }
  else {
    float r = sqrtf(f * f + g * g);
    float c = f / r, s = g / r;
    if (fabsf(f) > fabsf(g) && c < 0.f) { c = -c; s = -s; r = -r; }
    *cs = c; *sn = s; *rr = r;
  }
#endif
}

__device__ __forceinline__ void slaev2f(float a, float b, float c,
                                        float* rt1, float* rt2, float* cs1, float* sn1) {
#pragma clang fp contract(off)
  float sm = a + c, df = a - c, adf = fabsf(df);
  float tb = b + b, ab = fabsf(tb);
  float acmx, acmn;
  if (fabsf(a) > fabsf(c)) { acmx = a; acmn = c; } else { acmx = c; acmn = a; }
  float rt;
  if (adf > ab)      { float t = ab / adf; rt = adf * sqrtf(1.f + t * t); }
  else if (adf < ab) { float t = adf / ab; rt = ab * sqrtf(1.f + t * t); }
  else               { rt = ab * sqrtf(2.f); }
  int sgn1;
  if (sm < 0.f)      { *rt1 = 0.5f * (sm - rt); sgn1 = -1; *rt2 = (acmx / *rt1) * acmn - (b / *rt1) * b; }
  else if (sm > 0.f) { *rt1 = 0.5f * (sm + rt); sgn1 = 1;  *rt2 = (acmx / *rt1) * acmn - (b / *rt1) * b; }
  else               { *rt1 = 0.5f * rt; *rt2 = -0.5f * rt; sgn1 = 1; }
  float cs; int sgn2;
  if (df >= 0.f) { cs = df + rt; sgn2 = 1; } else { cs = df - rt; sgn2 = -1; }
  float acs = fabsf(cs);
  if (acs > ab) {
    float ct = -tb / cs;
    *sn1 = 1.f / sqrtf(1.f + ct * ct);
    *cs1 = ct * *sn1;
  } else {
    if (ab == 0.f) { *cs1 = 1.f; *sn1 = 0.f; }
    else {
      float tn = -cs / tb;
      *cs1 = 1.f / sqrtf(1.f + tn * tn);
      *sn1 = tn * *cs1;
    }
  }
  if (sgn1 == sgn2) { float tn = *cs1; *cs1 = -*sn1; *sn1 = tn; }
}

// ssyevd path for 3x3 (lower). Z/d/e/cw/sw in thread-strided LDS (FS stride).
#define FS 64
#define Zm(i_, j_) ldsZ[(((i_) * 3 + (j_)) ) * FS]
#define dm(i_)     ldsD[(i_) * FS]
#define em(i_)     ldsE[(i_) * FS]
#define cwm(i_)    ldsCW[(i_) * FS]
#define swm(i_)    ldsSW[(i_) * FS]

__device__ void eig3_lapack_lds(float a00, float a10, float a11, float a20, float a21, float a22,
                                float* __restrict__ ldsZ, float* __restrict__ ldsD,
                                float* __restrict__ ldsE, float* __restrict__ ldsCW,
                                float* __restrict__ ldsSW,
                                float vec[3], float eval[3]) {
#pragma clang fp contract(off)
  const float eps    = 5.9604645e-08f;
  const float eps2   = 3.5527137e-15f;
  const float safmin = 1.17549435e-38f;
  const float ssfmax = 3.0744573e18f;
  const float ssfmin = 3.0517578e-05f;

  float tau, v2;

  // ---- ssytd2 'L' ----
  {
    float alpha = a10, xx = a20;
    if (xx == 0.f) {
      tau = 0.f; v2 = 0.f;
      em(0) = alpha;
      dm(0) = a00; dm(1) = a11; dm(2) = a22; em(1) = a21;
    } else {
      float xnorm = fabsf(xx);
      float beta = -copysignf(slapy2f(alpha, xnorm), alpha);
      tau = (beta - alpha) / beta;
      float sc = 1.f / (alpha - beta);
      v2 = xx * sc;
      em(0) = beta;
      float x1 = tau * a11 + tau * (a21 * v2);
      float x2 = tau * a21 + (tau * v2) * a22;
      float dotxv = x1 + x2 * v2;
      float aw = (-0.5f * tau) * dotxv;
      float w1 = x1 + aw;
      float w2 = x2 + aw * v2;
      dm(0) = a00;
      dm(1) = (a11 - w1) - w1;
      em(1) = (a21 - v2 * w1) - w2;
      dm(2) = (a22 - v2 * w2) - w2 * v2;
    }
  }
  Zm(0,0) = 1.f; Zm(0,1) = 0.f; Zm(0,2) = 0.f;
  Zm(1,0) = 0.f; Zm(1,1) = 1.f; Zm(1,2) = 0.f;
  Zm(2,0) = 0.f; Zm(2,1) = 0.f; Zm(2,2) = 1.f;

  int nmaxit = 90, jtot = 0, l1 = 1;
  int l = 0, lsv = 0, lend = 0, lendsv = 0, m = 0, iscale = 0;
  float anorm = 0.f, p = 0.f, g = 0.f, r = 0.f, c = 0.f, s = 0.f, rt1 = 0.f, rt2 = 0.f;
  cwm(0) = 0.f; cwm(1) = 0.f; swm(0) = 0.f; swm(1) = 0.f;

L10:
  if (l1 > 3) goto L160;
  if (l1 > 1) em(l1 - 2) = 0.f;
  if (l1 <= 2) {
    for (m = l1; m <= 2; ++m) {
      float tst = fabsf(em(m - 1));
      if (tst == 0.f) goto L30;
      if (tst <= (sqrtf(fabsf(dm(m - 1))) * sqrtf(fabsf(dm(m)))) * eps) { em(m - 1) = 0.f; goto L30; }
    }
  }
  m = 3;
L30:
  l = l1; lsv = l; lend = m; lendsv = lend; l1 = m + 1;
  if (lend == l) goto L10;
  anorm = fabsf(dm(lend - 1));
  for (int i = l; i < lend; ++i) {
    anorm = fmaxf(anorm, fabsf(dm(i - 1)));
    anorm = fmaxf(anorm, fabsf(em(i - 1)));
  }
  iscale = 0;
  if (anorm == 0.f) goto L10;
  if (anorm > ssfmax) {
    iscale = 1;
    float mul = ssfmax / anorm;
    for (int i = l; i <= lend; ++i) dm(i - 1) = dm(i - 1) * mul;
    for (int i = l; i < lend; ++i) em(i - 1) = em(i - 1) * mul;
  } else if (anorm < ssfmin) {
    iscale = 2;
    float mul = ssfmin / anorm;
    for (int i = l; i <= lend; ++i) dm(i - 1) = dm(i - 1) * mul;
    for (int i = l; i < lend; ++i) em(i - 1) = em(i - 1) * mul;
  }
  if (fabsf(dm(lend - 1)) < fabsf(dm(l - 1))) { lend = lsv; l = lendsv; }
  if (lend > l) goto L40; else goto L90;

  // ================= QL =================
L40:
  if (l != lend) {
    for (m = l; m <= lend - 1; ++m) {
      float tst = em(m - 1) * em(m - 1);
      if (tst <= (eps2 * fabsf(dm(m - 1))) * fabsf(dm(m)) + safmin) goto L60;
    }
  }
  m = lend;
L60:
  if (m < lend) em(m - 1) = 0.f;
  p = dm(l - 1);
  if (m == l) goto L80;
  if (m == l + 1) {
    slaev2f(dm(l - 1), em(l - 1), dm(l), &rt1, &rt2, &c, &s);
    for (int i = 0; i < 3; ++i) {
      float t0 = Zm(i, l), t1 = Zm(i, l - 1);
      Zm(i, l)     = c * t0 - s * t1;
      Zm(i, l - 1) = s * t0 + c * t1;
    }
    dm(l - 1) = rt1; dm(l) = rt2; em(l - 1) = 0.f;
    l += 2;
    if (l <= lend) goto L40;
    goto L140;
  }
  if (jtot == nmaxit) goto L140;
  ++jtot;
  g = (dm(l) - p) / (2.f * em(l - 1));
  r = slapy2f(g, 1.f);
  g = dm(m - 1) - p + em(l - 1) / (g + copysignf(r, g));
  s = 1.f; c = 1.f; p = 0.f;
  for (int i = m - 1; i >= l; --i) {
    float f = s * em(i - 1);
    float bb = c * em(i - 1);
    slartgf(g, f, &c, &s, &r);
    if (i != m - 1) em(i) = r;
    g = dm(i) - p;
    r = (dm(i - 1) - g) * s + 2.f * c * bb;
    p = s * r;
    dm(i) = g + p;
    g = c * r - bb;
    cwm(i - 1) = c; swm(i - 1) = -s;
  }
  {
    int mm = m - l + 1;
    for (int j = mm - 1; j >= 1; --j) {      // SLASR 'R','V','B'
      float ct = cwm(l + j - 2), st = swm(l + j - 2);
      int hi = (l - 1) + j;
      for (int i = 0; i < 3; ++i) {
        float t0 = Zm(i, hi), t1 = Zm(i, hi - 1);
        Zm(i, hi)     = ct * t0 - st * t1;
        Zm(i, hi - 1) = st * t0 + ct * t1;
      }
    }
  }
  dm(l - 1) = dm(l - 1) - p;
  em(l - 1) = g;
  goto L40;
L80:
  dm(l - 1) = p;
  ++l;
  if (l <= lend) goto L40;
  goto L140;

  // ================= QR =================
L90:
  if (l != lend) {
    for (m = l; m >= lend + 1; --m) {
      float tst = em(m - 2) * em(m - 2);
      if (tst <= (eps2 * fabsf(dm(m - 1))) * fabsf(dm(m - 2)) + safmin) goto L110;
    }
  }
  m = lend;
L110:
  if (m > lend) em(m - 2) = 0.f;
  p = dm(l - 1);
  if (m == l) goto L130;
  if (m == l - 1) {
    slaev2f(dm(l - 2), em(l - 2), dm(l - 1), &rt1, &rt2, &c, &s);
    for (int i = 0; i < 3; ++i) {            // SLASR 'R','V','F' single rot
      float t0 = Zm(i, l - 1), t1 = Zm(i, l - 2);
      Zm(i, l - 1) = c * t0 - s * t1;
      Zm(i, l - 2) = s * t0 + c * t1;
    }
    dm(l - 2) = rt1; dm(l - 1) = rt2; em(l - 2) = 0.f;
    l -= 2;
    if (l >= lend) goto L90;
    goto L140;
  }
  if (jtot == nmaxit) goto L140;
  ++jtot;
  g = (dm(l - 2) - p) / (2.f * em(l - 2));
  r = slapy2f(g, 1.f);
  g = dm(m - 1) - p + em(l - 2) / (g + copysignf(r, g));
  s = 1.f; c = 1.f; p = 0.f;
  for (int i = m; i <= l - 1; ++i) {
    float f = s * em(i - 1);
    float bb = c * em(i - 1);
    slartgf(g, f, &c, &s, &r);
    if (i != m) em(i - 2) = r;
    g = dm(i - 1) - p;
    r = (dm(i) - g) * s + 2.f * c * bb;
    p = s * r;
    dm(i - 1) = g + p;
    g = c * r - bb;
    cwm(i - 1) = c; swm(i - 1) = s;
  }
  {
    int mm = l - m + 1;
    for (int j = 1; j <= mm - 1; ++j) {      // SLASR 'R','V','F'
      float ct = cwm(m + j - 2), st = swm(m + j - 2);
      int lo = (m - 1) + (j - 1);
      for (int i = 0; i < 3; ++i) {
        float t0 = Zm(i, lo + 1), t1 = Zm(i, lo);
        Zm(i, lo + 1) = ct * t0 - st * t1;
        Zm(i, lo)     = st * t0 + ct * t1;
      }
    }
  }
  dm(l - 1) = dm(l - 1) - p;
  em(l - 2) = g;
  goto L90;
L130:
  dm(l - 1) = p;
  --l;
  if (l >= lend) goto L90;
  goto L140;

L140:
  if (iscale == 1) {
    float mul = anorm / ssfmax;
    for (int i = lsv; i <= lendsv; ++i) dm(i - 1) = dm(i - 1) * mul;
    for (int i = lsv; i < lendsv; ++i) em(i - 1) = em(i - 1) * mul;
  } else if (iscale == 2) {
    float mul = anorm / ssfmin;
    for (int i = lsv; i <= lendsv; ++i) dm(i - 1) = dm(i - 1) * mul;
    for (int i = lsv; i < lendsv; ++i) em(i - 1) = em(i - 1) * mul;
  }
  if (jtot < nmaxit) goto L10;
  goto L160;

L160:
  for (int ii = 2; ii <= 3; ++ii) {
    int i0 = ii - 1, k = i0;
    float pp = dm(i0 - 1);
    for (int j = ii; j <= 3; ++j) {
      if (dm(j - 1) < pp) { k = j; pp = dm(j - 1); }
    }
    if (k != i0) {
      dm(k - 1) = dm(i0 - 1); dm(i0 - 1) = pp;
      for (int rr2 = 0; rr2 < 3; ++rr2) {
        float t = Zm(rr2, i0 - 1); Zm(rr2, i0 - 1) = Zm(rr2, k - 1); Zm(rr2, k - 1) = t;
      }
    }
  }
  if (tau != 0.f) {
    for (int j = 0; j < 3; ++j) {
      float wj = Zm(1, j) + v2 * Zm(2, j);
      Zm(1, j) = Zm(1, j) - tau * wj;
      Zm(2, j) = Zm(2, j) - (tau * wj) * v2;
    }
  }
  vec[0] = Zm(0, 0); vec[1] = Zm(1, 0); vec[2] = Zm(2, 0);
  eval[0] = dm(0); eval[1] = dm(1); eval[2] = dm(2);
}

// ------- branchless sorted top-20 insert, lexicographic (d2, j) key -------
__device__ __forceinline__ void insert20lex(float d2, int j, float bd[KNN], int bi[KNN]) {
  bool c[KNN];
#pragma unroll
  for (int k = 0; k < KNN; ++k)
    c[k] = (d2 < bd[k]) || (d2 == bd[k] && j < bi[k]);
#pragma unroll
  for (int k = KNN - 1; k >= 1; --k) {
    bd[k] = c[k - 1] ? bd[k - 1] : (c[k] ? d2 : bd[k]);
    bi[k] = c[k - 1] ? bi[k - 1] : (c[k] ? j : bi[k]);
  }
  bd[0] = c[0] ? d2 : bd[0];
  bi[0] = c[0] ? j : bi[0];
}

// ---------------- Kernels ----------------

__global__ void prep_kernel(const float* __restrict__ pc, float4* __restrict__ pts4, int total) {
  int i = blockIdx.x * blockDim.x + threadIdx.x;
  if (i < total) {
    float x = pc[i * 3 + 0], y = pc[i * 3 + 1], z = pc[i * 3 + 2];
    pts4[i] = make_float4(x, y, z, fmaf(z, z, fmaf(y, y, x * x)));
  }
}

// Transpose weights for channel-per-lane coalesced access.
// W1T[i*64+c]          = W1[c*9+i]
// W2T2[(i*64+l)*2+k]   = W2[(l+64k)*64+i]
// W3T4[(i*64+l)*4+k]   = W3[(l+64k)*128+i]
__global__ void prep_w_kernel(const float* __restrict__ W1, const float* __restrict__ W2,
                              const float* __restrict__ W3, float* __restrict__ W1T,
                              float* __restrict__ W2T2, float* __restrict__ W3T4) {
  int f = blockIdx.x * 256 + threadIdx.x;          // 0..32767
  {
    int k = f & 3, l = (f >> 2) & 63, i = f >> 8;
    W3T4[f] = W3[(l + 64 * k) * 128 + i];
  }
  if (f < 8192) {
    int k = f & 1, l = (f >> 1) & 63, i = f >> 7;
    W2T2[f] = W2[(l + 64 * k) * 64 + i];
  }
  if (f < 576) {
    int i = f >> 6, c = f & 63;
    W1T[f] = W1[c * 9 + i];
  }
}

// Scan kernel: 32 queries x 8 subs (256 thr). Pass1: register top-3 per sub;
// thr = max of 8 sub-thirds. Pass2: pooled index collect (ushort). Merge
// recomputes d2 (identical bits). Exact fallback if raw<20 or raw>CAPS.
__global__ __launch_bounds__(256) void knn_scan_kernel(const float4* __restrict__ pts4,
                                                       float* __restrict__ knnd,
                                                       int* __restrict__ knni, int total) {
  __shared__ float  sub3[SUBS][QPB];
  __shared__ unsigned short ibuf[CAPS][QPB];
  __shared__ int    qcnt[QPB];

  const int t = threadIdx.x;
  const int q = t & (QPB - 1);
  const int s = t >> 5;
  const int b = blockIdx.x >> 7;
  const int n = ((blockIdx.x & 127) << 5) + q;
  const int p = (b << 12) + n;
  const float4* __restrict__ P = pts4 + ((size_t)b << 12);
  const float4 me = P[n];
  const float xi = me.x, yi = me.y, zi = me.z, sqi = me.w;

  if (t < QPB) qcnt[t] = 0;

  const int j0 = s << 9;
  float t0 = __builtin_inff(), t1 = __builtin_inff(), t2 = __builtin_inff();
  for (int jj = 0; jj < 512; jj += 8) {
    float4 cc[8];
#pragma unroll
    for (int u = 0; u < 8; ++u) cc[u] = P[j0 + jj + u];
#pragma unroll
    for (int u = 0; u < 8; ++u) {
      float dot = fmaf(zi, cc[u].z, fmaf(yi, cc[u].y, xi * cc[u].x));
      float d2 = fmaf(-2.f, dot, sqi + cc[u].w);
      bool c0 = d2 < t0, c1 = d2 < t1, c2 = d2 < t2;
      t2 = c1 ? t1 : (c2 ? d2 : t2);
      t1 = c0 ? t0 : (c1 ? d2 : t1);
      t0 = c0 ? d2 : t0;
    }
  }
  sub3[s][q] = t2;
  __syncthreads();

  float thr = sub3[0][q];
#pragma unroll
  for (int k = 1; k < SUBS; ++k) thr = fmaxf(thr, sub3[k][q]);

  for (int jj = 0; jj < 512; jj += 8) {
    float4 cc[8];
#pragma unroll
    for (int u = 0; u < 8; ++u) cc[u] = P[j0 + jj + u];
#pragma unroll
    for (int u = 0; u < 8; ++u) {
      float dot = fmaf(zi, cc[u].z, fmaf(yi, cc[u].y, xi * cc[u].x));
      float d2 = fmaf(-2.f, dot, sqi + cc[u].w);
      if (d2 < thr) {
        int slot = atomicAdd(&qcnt[q], 1);
        if (slot < CAPS) ibuf[slot][q] = (unsigned short)(j0 + jj + u);
      }
    }
  }
  __syncthreads();

  if (s != 0) return;

  float bd[KNN]; int bi[KNN];
#pragma unroll
  for (int k = 0; k < KNN; ++k) { bd[k] = __builtin_inff(); bi[k] = 0; }

  const int raw = qcnt[q];
  const int cnt = min(raw, CAPS);
  const bool bad = (raw > CAPS) || (raw < KNN);
  for (int i = 0; i < CAPS; ++i) {
    if (__all(i >= cnt)) break;
    if (i < cnt) {
      int jj = ibuf[i][q];
      float4 cj = P[jj];
      float dot = fmaf(zi, cj.z, fmaf(yi, cj.y, xi * cj.x));
      float d2 = fmaf(-2.f, dot, sqi + cj.w);
      if (d2 < bd[KNN - 1] || (d2 == bd[KNN - 1] && jj < bi[KNN - 1]))
        insert20lex(d2, jj, bd, bi);
    }
  }
  if (__any(bad)) {
    if (bad) {
#pragma unroll
      for (int k = 0; k < KNN; ++k) { bd[k] = __builtin_inff(); bi[k] = 0; }
    }
    for (int j = 0; j < NPT; ++j) {
      float4 cj = P[j];
      float dot = fmaf(zi, cj.z, fmaf(yi, cj.y, xi * cj.x));
      float d2 = fmaf(-2.f, dot, sqi + cj.w);
      if (bad && (d2 < bd[KNN - 1] || (d2 == bd[KNN - 1] && j < bi[KNN - 1])))
        insert20lex(d2, j, bd, bi);
    }
  }

#pragma unroll
  for (int k = 0; k < KNN; ++k) {
    knnd[k * total + p] = bd[k];
    knni[k * total + p] = bi[k];
  }
}

// One thread per query: gather 20 neighbors, dist feats + covariance + eig.
__global__ __launch_bounds__(64) void feat_kernel(const float4* __restrict__ pts4,
                                                  const float* __restrict__ knnd,
                                                  const int* __restrict__ knni,
                                                  float* __restrict__ feat, int total) {
  __shared__ float eZ[9 * FS];
  __shared__ float eD[3 * FS];
  __shared__ float eE[2 * FS];
  __shared__ float eCW[2 * FS];
  __shared__ float eSW[2 * FS];

  const int tid = threadIdx.x;
  const int p = blockIdx.x * 64 + tid;
  const int b = p >> 12;
  const float4* __restrict__ P = pts4 + ((size_t)b << 12);
  const float4 me = P[p & 4095];
  const float xi = me.x, yi = me.y, zi = me.z;

  float bd[KNN]; int bi[KNN];
#pragma unroll
  for (int k = 0; k < KNN; ++k) {
    bd[k] = knnd[k * total + p];
    bi[k] = knni[k * total + p];
  }

  float sumd = 0.f, maxd = 0.f, mux = 0.f, muy = 0.f, muz = 0.f;
#pragma unroll
  for (int k = 0; k < KNN; ++k) {
    float dist = sqrtf(fmaxf(bd[k], 0.f) + 1e-12f);
    sumd += dist;
    maxd = fmaxf(maxd, dist);
    float4 nb = P[bi[k]];
    mux += nb.x; muy += nb.y; muz += nb.z;
  }
  float meand = sumd / 20.f;
  mux /= 20.f; muy /= 20.f; muz /= 20.f;

  float cxx = 0.f, cxy = 0.f, cxz = 0.f, cyy = 0.f, cyz = 0.f, czz = 0.f;
#pragma unroll
  for (int k = 0; k < KNN; ++k) {
    float4 nb = P[bi[k]];
    float dx = nb.x - mux, dy = nb.y - muy, dz = nb.z - muz;
    cxx = fmaf(dx, dx, cxx); cxy = fmaf(dx, dy, cxy); cxz = fmaf(dx, dz, cxz);
    cyy = fmaf(dy, dy, cyy); cyz = fmaf(dy, dz, cyz); czz = fmaf(dz, dz, czz);
  }
  cxx /= 20.f; cxy /= 20.f; cxz /= 20.f; cyy /= 20.f; cyz /= 20.f; czz /= 20.f;

  float vec[3], ev[3];
  eig3_lapack_lds(cxx, cxy, cyy, cxz, cyz, czz,
                  &eZ[tid], &eD[tid], &eE[tid], &eCW[tid], &eSW[tid], vec, ev);
  float curv = ev[0] / (((ev[0] + ev[1]) + ev[2]) + 1e-8f);

  feat[0 * total + p] = xi;
  feat[1 * total + p] = yi;
  feat[2 * total + p] = zi;
  feat[3 * total + p] = vec[0];
  feat[4 * total + p] = vec[1];
  feat[5 * total + p] = vec[2];
  feat[6 * total + p] = curv;
  feat[7 * total + p] = meand;
  feat[8 * total + p] = maxd;
}

// GEMM-style MLP. Block = 64 points, 4 waves; wave w owns 16 points with a
// private LDS slice. Lanes = output channels; weights pre-transposed so each
// lane vector-loads its own channels' weights (coalesced); activations
// broadcast from LDS (ds_read_b128); register accumulator tiles.
#define NPW 16   // points per wave
#define HPAD 20  // LDS row pad (floats): 80B rows keep float4 alignment

__global__ __launch_bounds__(256) void mlp_kernel(const float* __restrict__ feat,
    const float* __restrict__ W1T, const float* __restrict__ B1,
    const float* __restrict__ W2T2, const float* __restrict__ B2,
    const float* __restrict__ W3T4, const float* __restrict__ B3,
    float* __restrict__ out, int total) {
  __shared__ float feats[4][9][NPW];
  __shared__ float h1s[4][64][HPAD];
  __shared__ float h2s[4][128][HPAD];

  const int t = threadIdx.x;
  const int l = t & 63;
  const int w = t >> 6;
  const int p0 = blockIdx.x * 64 + w * NPW;
  const int b = p0 >> 12;
  const int n0 = p0 & 4095;

  // ---- stage feat tile (16 points x 9 channels) ----
  if (l < NPW) {
#pragma unroll
    for (int c = 0; c < 9; ++c) feats[w][c][l] = feat[c * total + p0 + l];
  }
  __syncthreads();

  // ---- layer 1: lane = h1 channel, 9 weights hoisted to registers ----
  float w1r[9];
#pragma unroll
  for (int i = 0; i < 9; ++i) w1r[i] = W1T[i * 64 + l];
  const float b1v = B1[l];
#pragma unroll
  for (int pp = 0; pp < NPW; ++pp) {
    float acc = b1v;
#pragma unroll
    for (int i = 0; i < 9; ++i) acc = fmaf(feats[w][i][pp], w1r[i], acc);
    h1s[w][l][pp] = fmaxf(acc, 0.f);
  }
  __syncthreads();

  // ---- layer 2: lane owns h2 channels l and l+64 ----
  float a2x[NPW], a2y[NPW];
  {
    const float b2x = B2[l], b2y = B2[l + 64];
#pragma unroll
    for (int pp = 0; pp < NPW; ++pp) { a2x[pp] = b2x; a2y[pp] = b2y; }
  }
#pragma unroll 4
  for (int i = 0; i < 64; ++i) {
    const float2 wv = *(const float2*)&W2T2[(i * 64 + l) * 2];
    const float* hrow = &h1s[w][i][0];
#pragma unroll
    for (int qd = 0; qd < 4; ++qd) {
      float4 h4 = *(const float4*)&hrow[qd * 4];
      a2x[qd * 4 + 0] = fmaf(h4.x, wv.x, a2x[qd * 4 + 0]);
      a2x[qd * 4 + 1] = fmaf(h4.y, wv.x, a2x[qd * 4 + 1]);
      a2x[qd * 4 + 2] = fmaf(h4.z, wv.x, a2x[qd * 4 + 2]);
      a2x[qd * 4 + 3] = fmaf(h4.w, wv.x, a2x[qd * 4 + 3]);
      a2y[qd * 4 + 0] = fmaf(h4.x, wv.y, a2y[qd * 4 + 0]);
      a2y[qd * 4 + 1] = fmaf(h4.y, wv.y, a2y[qd * 4 + 1]);
      a2y[qd * 4 + 2] = fmaf(h4.z, wv.y, a2y[qd * 4 + 2]);
      a2y[qd * 4 + 3] = fmaf(h4.w, wv.y, a2y[qd * 4 + 3]);
    }
  }
#pragma unroll
  for (int pp = 0; pp < NPW; ++pp) {
    h2s[w][l][pp]      = fmaxf(a2x[pp], 0.f);
    h2s[w][l + 64][pp] = fmaxf(a2y[pp], 0.f);
  }
  __syncthreads();

  // ---- layer 3: lane owns out channels l, l+64, l+128, l+192 ----
  float a30[NPW], a31[NPW], a32[NPW], a33[NPW];
  {
    const float b0 = B3[l], c1v = B3[l + 64], c2v = B3[l + 128], c3v = B3[l + 192];
#pragma unroll
    for (int pp = 0; pp < NPW; ++pp) { a30[pp] = b0; a31[pp] = c1v; a32[pp] = c2v; a33[pp] = c3v; }
  }
#pragma unroll 2
  for (int i = 0; i < 128; ++i) {
    const float4 wv = *(const float4*)&W3T4[(i * 64 + l) * 4];
    const float* hrow = &h2s[w][i][0];
#pragma unroll
    for (int qd = 0; qd < 4; ++qd) {
      float4 h4 = *(const float4*)&hrow[qd * 4];
      a30[qd * 4 + 0] = fmaf(h4.x, wv.x, a30[qd * 4 + 0]);
      a30[qd * 4 + 1] = fmaf(h4.y, wv.x, a30[qd * 4 + 1]);
      a30[qd * 4 + 2] = fmaf(h4.z, wv.x, a30[qd * 4 + 2]);
      a30[qd * 4 + 3] = fmaf(h4.w, wv.x, a30[qd * 4 + 3]);
      a31[qd * 4 + 0] = fmaf(h4.x, wv.y, a31[qd * 4 + 0]);
      a31[qd * 4 + 1] = fmaf(h4.y, wv.y, a31[qd * 4 + 1]);
      a31[qd * 4 + 2] = fmaf(h4.z, wv.y, a31[qd * 4 + 2]);
      a31[qd * 4 + 3] = fmaf(h4.w, wv.y, a31[qd * 4 + 3]);
      a32[qd * 4 + 0] = fmaf(h4.x, wv.z, a32[qd * 4 + 0]);
      a32[qd * 4 + 1] = fmaf(h4.y, wv.z, a32[qd * 4 + 1]);
      a32[qd * 4 + 2] = fmaf(h4.z, wv.z, a32[qd * 4 + 2]);
      a32[qd * 4 + 3] = fmaf(h4.w, wv.z, a32[qd * 4 + 3]);
      a33[qd * 4 + 0] = fmaf(h4.x, wv.w, a33[qd * 4 + 0]);
      a33[qd * 4 + 1] = fmaf(h4.y, wv.w, a33[qd * 4 + 1]);
      a33[qd * 4 + 2] = fmaf(h4.z, wv.w, a33[qd * 4 + 2]);
      a33[qd * 4 + 3] = fmaf(h4.w, wv.w, a33[qd * 4 + 3]);
    }
  }

  // ---- stores: per channel row, 16 consecutive floats (4x float4/lane) ----
  float* op = out + (size_t)b * (256 * 4096) + n0;
#define STORE_GRP(arr_, k_)                                                   \
  {                                                                           \
    float* row = op + (size_t)(l + (k_) * 64) * 4096;                         \
    *(float4*)&row[0]  = make_float4(arr_[0],  arr_[1],  arr_[2],  arr_[3]);  \
    *(float4*)&row[4]  = make_float4(arr_[4],  arr_[5],  arr_[6],  arr_[7]);  \
    *(float4*)&row[8]  = make_float4(arr_[8],  arr_[9],  arr_[10], arr_[11]); \
    *(float4*)&row[12] = make_float4(arr_[12], arr_[13], arr_[14], arr_[15]); \
  }
  STORE_GRP(a30, 0)
  STORE_GRP(a31, 1)
  STORE_GRP(a32, 2)
  STORE_GRP(a33, 3)
#undef STORE_GRP
}

extern "C" void kernel_launch(void* const* d_in, const int* in_sizes, int n_in,
                              void* d_out, int out_size, void* d_ws, size_t ws_size,
                              hipStream_t stream) {
  const float* pc = (const float*)d_in[0];
  const float* W1 = (const float*)d_in[1];
  const float* b1 = (const float*)d_in[2];
  const float* W2 = (const float*)d_in[3];
  const float* b2 = (const float*)d_in[4];
  const float* W3 = (const float*)d_in[5];
  const float* b3 = (const float*)d_in[6];
  // d_in[7] = vis_mask (all ones) -- unused, matches reference semantics

  const int total = in_sizes[0] / 3;               // B*N = 32768
  float* wsf = (float*)d_ws;
  float* W1T  = wsf;                                // 576   (pad to 1024)
  float* W2T2 = wsf + 1024;                         // 8192
  float* W3T4 = wsf + 1024 + 8192;                  // 32768
  float4* pts4 = (float4*)(wsf + 41984);            // 16B-aligned (41984*4 % 16 == 0)
  float* feat = wsf + 41984 + total * 4;
  float* outp = (float*)d_out;
  // Stage top-20 lists in d_out (5.2 MB of 32 MB), overwritten by MLP later.
  float* knnd = outp;
  int*   knni = (int*)(outp + (size_t)KNN * total);

  prep_kernel<<<(total + 255) / 256, 256, 0, stream>>>(pc, pts4, total);
  prep_w_kernel<<<128, 256, 0, stream>>>(W1, W2, W3, W1T, W2T2, W3T4);
  knn_scan_kernel<<<total / QPB, 256, 0, stream>>>(pts4, knnd, knni, total);
  feat_kernel<<<total / 64, 64, 0, stream>>>(pts4, knnd, knni, feat, total);
  mlp_kernel<<<total / 64, 256, 0, stream>>>(feat, W1T, b1, W2T2, b2, W3T4, b3, outp, total);
}